// Round 1
// baseline (667.862 us; speedup 1.0000x reference)
//
#include <hip/hip_runtime.h>
#include <hip/hip_bf16.h>
#include <math.h>

// ---------------------------------------------------------------------------
// DogeCDMoE: q-proj GEMM -> product-key top-k -> expert gather/accumulate
//            + dense MLP (gate/up/silu-mul/down) ; out = mlp + experts
// Round 1: correct fp32 baseline (vector ALU). MFMA conversion planned next.
// ---------------------------------------------------------------------------

#define TOKENS 2048
#define DIM    1024
#define INTER  2048
#define NKEYS  128
#define TOPK   8
#define HEADS  4

// ---------------- GEMM: C[M,N] = A[M,K] @ W[N,K]^T  (both row-major) --------
// EPI 0: C = acc
// EPI 1: C = silu(extra) * acc        (extra = gate buffer, acc = up)
// EPI 2: C = acc + extra              (extra = experts_states)
template<int EPI>
__global__ __launch_bounds__(256) void gemm_nt(const float* __restrict__ A,
                                               const float* __restrict__ W,
                                               const float* __restrict__ extra,
                                               float* __restrict__ C,
                                               int M, int N, int K) {
    __shared__ __align__(16) float As[16][68];   // [k][m], +4 pad keeps f4 align
    __shared__ __align__(16) float Ws[16][68];   // [k][n]
    const int tid = threadIdx.x;
    const int tx = tid & 15, ty = tid >> 4;
    const int m0 = blockIdx.y * 64, n0 = blockIdx.x * 64;
    const int li = tid >> 2;            // 0..63 : row of tile
    const int lj = (tid & 3) << 2;      // 0,4,8,12 : k-offset (float4)
    const float* Ap = &A[(size_t)(m0 + li) * K + lj];
    const float* Wp = &W[(size_t)(n0 + li) * K + lj];

    float acc[4][4] = {};
    for (int k0 = 0; k0 < K; k0 += 16) {
        const float4 av = *(const float4*)(Ap + k0);
        const float4 wv = *(const float4*)(Wp + k0);
        __syncthreads();
        As[lj + 0][li] = av.x; As[lj + 1][li] = av.y;
        As[lj + 2][li] = av.z; As[lj + 3][li] = av.w;
        Ws[lj + 0][li] = wv.x; Ws[lj + 1][li] = wv.y;
        Ws[lj + 2][li] = wv.z; Ws[lj + 3][li] = wv.w;
        __syncthreads();
#pragma unroll
        for (int kk = 0; kk < 16; ++kk) {
            const float4 a = *(const float4*)&As[kk][ty << 2];
            const float4 b = *(const float4*)&Ws[kk][tx << 2];
            acc[0][0] += a.x * b.x; acc[0][1] += a.x * b.y;
            acc[0][2] += a.x * b.z; acc[0][3] += a.x * b.w;
            acc[1][0] += a.y * b.x; acc[1][1] += a.y * b.y;
            acc[1][2] += a.y * b.z; acc[1][3] += a.y * b.w;
            acc[2][0] += a.z * b.x; acc[2][1] += a.z * b.y;
            acc[2][2] += a.z * b.z; acc[2][3] += a.z * b.w;
            acc[3][0] += a.w * b.x; acc[3][1] += a.w * b.y;
            acc[3][2] += a.w * b.z; acc[3][3] += a.w * b.w;
        }
    }
#pragma unroll
    for (int r = 0; r < 4; ++r) {
        const int m = m0 + (ty << 2) + r;
        const size_t base = (size_t)m * N + n0 + (tx << 2);
#pragma unroll
        for (int c = 0; c < 4; ++c) {
            float v = acc[r][c];
            if (EPI == 1) { const float g = extra[base + c]; v *= g / (1.f + expf(-g)); }
            if (EPI == 2) { v += extra[base + c]; }
            C[base + c] = v;
        }
    }
}

// ---------------- product-key routing: sim -> top8 x, top8 y, top8 of 64 ----
// q layout: q[t*256 + p*128 + head*32 + n]   (reshape (t,2,h,32) of 256-col)
// keys layout: keys[((head*128 + k)*2 + p)*32 + n]
__global__ __launch_bounds__(256) void topk_kernel(const float* __restrict__ q,
                                                   const float* __restrict__ keys,
                                                   int* __restrict__ eidx,
                                                   float* __restrict__ ewgt) {
    __shared__ float sim[HEADS][2 * NKEYS];
    __shared__ float comb[HEADS][64];
    __shared__ int   cidx[HEADS][64];
    const int t = blockIdx.x;
    const int head = threadIdx.x >> 6;
    const int lane = threadIdx.x & 63;

#pragma unroll
    for (int i = 0; i < 4; ++i) {
        const int pk = lane + 64 * i;        // p = pk>>7, k = pk&127
        const int p = pk >> 7, k = pk & 127;
        const float4* kv = (const float4*)&keys[(size_t)(((head << 7) | k) * 2 + p) * 32];
        const float4* qv = (const float4*)&q[(size_t)t * 256 + p * 128 + head * 32];
        float s = 0.f;
#pragma unroll
        for (int n = 0; n < 8; ++n) {
            const float4 a = qv[n], b = kv[n];
            s += a.x * b.x + a.y * b.y + a.z * b.z + a.w * b.w;
        }
        sim[head][pk] = s;
    }
    __syncthreads();

    if (lane == 0) {
        float sx[TOPK], sy[TOPK];
        int ixx[TOPK], iyy[TOPK];
        float* sp = sim[head];
        // top-8 of codebook x (destructive selection; strict > keeps first max,
        // matching jax.lax.top_k tie order)
#pragma unroll
        for (int it = 0; it < TOPK; ++it) {
            float best = -3.4e38f; int bi = 0;
            for (int k = 0; k < NKEYS; ++k)
                if (sp[k] > best) { best = sp[k]; bi = k; }
            sx[it] = best; ixx[it] = bi; sp[bi] = -3.4e38f;
        }
#pragma unroll
        for (int it = 0; it < TOPK; ++it) {
            float best = -3.4e38f; int bi = 0;
            for (int k = 0; k < NKEYS; ++k)
                if (sp[NKEYS + k] > best) { best = sp[NKEYS + k]; bi = k; }
            sy[it] = best; iyy[it] = bi; sp[NKEYS + bi] = -3.4e38f;
        }
        // cartesian 8x8 combine
#pragma unroll
        for (int a = 0; a < TOPK; ++a)
#pragma unroll
            for (int b = 0; b < TOPK; ++b) {
                comb[head][a * 8 + b] = sx[a] + sy[b];
                cidx[head][a * 8 + b] = ixx[a] * NKEYS + iyy[b];
            }
        // top-8 of 64
        float fs[TOPK]; int fi[TOPK];
        float* cp = comb[head];
#pragma unroll
        for (int it = 0; it < TOPK; ++it) {
            float best = -3.4e38f; int bp = 0;
            for (int j = 0; j < 64; ++j)
                if (cp[j] > best) { best = cp[j]; bp = j; }
            fs[it] = best; fi[it] = cidx[head][bp]; cp[bp] = -3.4e38f;
        }
        // softmax over the 8 selected scores
        float m = fs[0];
#pragma unroll
        for (int j = 1; j < TOPK; ++j) m = fmaxf(m, fs[j]);
        float e[TOPK], ssum = 0.f;
#pragma unroll
        for (int j = 0; j < TOPK; ++j) { e[j] = expf(fs[j] - m); ssum += e[j]; }
        const float inv = 1.f / ssum;
#pragma unroll
        for (int j = 0; j < TOPK; ++j) {
            eidx[t * 32 + head * 8 + j] = fi[j];
            ewgt[t * 32 + head * 8 + j] = e[j] * inv;
        }
    }
}

// ---------------- expert gather + weighted accumulate -----------------------
// estate[t,:] = sum_j silu(h_t . de[e_j]) * w_j * ue[e_j]
__global__ __launch_bounds__(256) void experts_kernel(const float* __restrict__ hs,
                                                      const float* __restrict__ down_embed,
                                                      const float* __restrict__ up_embed,
                                                      const int* __restrict__ eidx,
                                                      const float* __restrict__ ewgt,
                                                      float* __restrict__ estate) {
    __shared__ float4 h4[256];
    __shared__ float coeff[32];
    __shared__ int   eid[32];
    __shared__ float wl[32];
    const int t = blockIdx.x;
    const int tid = threadIdx.x;

    h4[tid] = ((const float4*)&hs[(size_t)t * DIM])[tid];
    if (tid < 32) { eid[tid] = eidx[t * 32 + tid]; wl[tid] = ewgt[t * 32 + tid]; }
    __syncthreads();

    const int w = tid >> 6, lane = tid & 63;
#pragma unroll
    for (int jj = 0; jj < 8; ++jj) {
        const int j = w * 8 + jj;
        const int e = eid[j];
        const float4* dr = (const float4*)&down_embed[(size_t)e * DIM];
        float s = 0.f;
#pragma unroll
        for (int c = 0; c < 4; ++c) {
            const float4 a = h4[c * 64 + lane];
            const float4 b = dr[c * 64 + lane];
            s += a.x * b.x + a.y * b.y + a.z * b.z + a.w * b.w;
        }
#pragma unroll
        for (int off = 32; off; off >>= 1) s += __shfl_down(s, off);
        if (lane == 0) coeff[j] = (s / (1.f + expf(-s))) * wl[j];
    }
    __syncthreads();

    float4 acc = {0.f, 0.f, 0.f, 0.f};
#pragma unroll 8
    for (int j = 0; j < 32; ++j) {
        const int e = eid[j];
        const float c = coeff[j];
        const float4 u = *(const float4*)&up_embed[(size_t)e * DIM + (size_t)tid * 4];
        acc.x += c * u.x; acc.y += c * u.y; acc.z += c * u.z; acc.w += c * u.w;
    }
    *(float4*)&estate[(size_t)t * DIM + (size_t)tid * 4] = acc;
}

// ---------------------------------------------------------------------------
extern "C" void kernel_launch(void* const* d_in, const int* in_sizes, int n_in,
                              void* d_out, int out_size, void* d_ws, size_t ws_size,
                              hipStream_t stream) {
    (void)in_sizes; (void)n_in; (void)out_size; (void)ws_size;
    const float* hidden = (const float*)d_in[0];
    const float* wq     = (const float*)d_in[1];
    const float* keys   = (const float*)d_in[2];
    const float* down_e = (const float*)d_in[3];
    const float* up_e   = (const float*)d_in[4];
    const float* wgate  = (const float*)d_in[5];
    const float* wup    = (const float*)d_in[6];
    const float* wdown  = (const float*)d_in[7];
    float* out = (float*)d_out;
    float* ws  = (float*)d_ws;

    // workspace layout (floats). estate aliases g: g is dead after the
    // up-GEMM (EPI1) consumes it, and experts_kernel runs after that.
    float* q      = ws;                       // 2048*256   = 524288
    float* act    = ws + 524288;              // 2048*2048  = 4194304
    float* g      = ws + 4718592;             // 2048*2048  = 4194304
    float* estate = g;                        // 2048*1024  = 2097152 (alias)
    float* wgt    = ws + 8912896;             // 2048*32    = 65536
    int*   eidx   = (int*)(ws + 8978432);     // 2048*32    = 65536
    // total: 9043968 floats = 36.2 MB

    // 1) q = hidden @ wq^T            (2048 x 256 x 1024)
    gemm_nt<0><<<dim3(256 / 64, TOKENS / 64), 256, 0, stream>>>(
        hidden, wq, nullptr, q, TOKENS, 256, DIM);
    // 2) product-key routing -> eidx, wgt
    topk_kernel<<<TOKENS, 256, 0, stream>>>(q, keys, eidx, wgt);
    // 3) g = hidden @ wgate^T         (2048 x 2048 x 1024)
    gemm_nt<0><<<dim3(INTER / 64, TOKENS / 64), 256, 0, stream>>>(
        hidden, wgate, nullptr, g, TOKENS, INTER, DIM);
    // 4) act = silu(g) * (hidden @ wup^T)
    gemm_nt<1><<<dim3(INTER / 64, TOKENS / 64), 256, 0, stream>>>(
        hidden, wup, g, act, TOKENS, INTER, DIM);
    // 5) experts_states (writes over g region -- g is dead now)
    experts_kernel<<<TOKENS, 256, 0, stream>>>(hidden, down_e, up_e, eidx, wgt, estate);
    // 6) out = act @ wdown^T + estate (2048 x 1024 x 2048)
    gemm_nt<2><<<dim3(DIM / 64, TOKENS / 64), 256, 0, stream>>>(
        act, wdown, estate, out, TOKENS, DIM, INTER);
}

// Round 2
// 347.333 us; speedup vs baseline: 1.9228x; 1.9228x over previous
//
#include <hip/hip_runtime.h>
#include <hip/hip_bf16.h>
#include <math.h>

// ---------------------------------------------------------------------------
// DogeCDMoE round 2: bf16 MFMA GEMMs (m97-style: global_load_lds staging,
// ds_read_b128 fragments, 16x16x32 bf16 MFMA) + fused epilogues.
// topk/experts unchanged from the passing fp32 baseline.
// ---------------------------------------------------------------------------

#define TOKENS 2048
#define DIM    1024
#define INTER  2048
#define NKEYS  128
#define TOPK   8
#define HEADS  4

typedef unsigned short ushort_t;
typedef __attribute__((ext_vector_type(8))) short bf16x8;
typedef __attribute__((ext_vector_type(4))) float f32x4;

__device__ __forceinline__ float bf2f(ushort_t u) {
    unsigned int x = (unsigned int)u << 16;
    float f; __builtin_memcpy(&f, &x, 4); return f;
}
__device__ __forceinline__ ushort_t f2bf_rne(float f) {
    unsigned int x; __builtin_memcpy(&x, &f, 4);
    x += 0x7fffu + ((x >> 16) & 1u);
    return (ushort_t)(x >> 16);
}
__device__ __forceinline__ void gload_lds16(const void* g, void* l) {
    __builtin_amdgcn_global_load_lds(
        (const __attribute__((address_space(1))) unsigned int*)g,
        (__attribute__((address_space(3))) unsigned int*)l, 16, 0, 0);
}

// ---------------- f32 -> bf16 (RNE), 8 elems/thread -------------------------
__global__ __launch_bounds__(256) void f32_to_bf16(const float* __restrict__ in,
                                                   ushort_t* __restrict__ out, int n8) {
    const int i = blockIdx.x * 256 + threadIdx.x;
    if (i >= n8) return;
    const float4* p = (const float4*)in + (size_t)i * 2;
    const float4 a = p[0], b = p[1];
    uint4 o;
    o.x = (unsigned)f2bf_rne(a.x) | ((unsigned)f2bf_rne(a.y) << 16);
    o.y = (unsigned)f2bf_rne(a.z) | ((unsigned)f2bf_rne(a.w) << 16);
    o.z = (unsigned)f2bf_rne(b.x) | ((unsigned)f2bf_rne(b.y) << 16);
    o.w = (unsigned)f2bf_rne(b.z) | ((unsigned)f2bf_rne(b.w) << 16);
    ((uint4*)out)[i] = o;
}

// ---------------- bf16 MFMA GEMM: C[M,N] = A[M,K] @ B[N,K]^T ----------------
// EPI 0: Cout f32 = acc
// EPI 1: Cout bf16 = silu(extra_bf16) * acc      (up-proj: act = silu(g)*up)
// EPI 2: Cout f32 = acc + extra_f32              (down-proj + experts add)
// EPI 3: Cout bf16 = acc                         (gate-proj)
// Tile: BM x BN x 32. 4 waves arranged WR x WC; per-wave FM x FN frags 16x16.
template<int BM, int BN, int WR, int WC, int FM, int FN, int EPI>
__global__ __launch_bounds__(256) void mfma_gemm(const ushort_t* __restrict__ A,
                                                 const ushort_t* __restrict__ B,
                                                 const void* __restrict__ extra,
                                                 void* __restrict__ Cout,
                                                 int M, int N, int K) {
    static_assert(WR * WC == 4 && WR * FM * 16 == BM && WC * FN * 16 == BN, "geom");
    __shared__ ushort_t As[BM * 32];
    __shared__ ushort_t Bs[BN * 32];
    const int tid = threadIdx.x;
    const int w = tid >> 6, lane = tid & 63;
    const int wr = w / WC, wc = w % WC;
    const int m0 = blockIdx.y * BM, n0 = blockIdx.x * BN;

    // staging: per-inst a wave fills 16 rows x 32 k (1KB), linear LDS order
    const int srow = (w << 4) + (lane >> 2);
    const int scol = (lane & 3) << 3;
    const ushort_t* Ag = &A[(size_t)(m0 + srow) * K + scol];
    const ushort_t* Bg = &B[(size_t)(n0 + srow) * K + scol];
    ushort_t* Al = &As[w << 9];
    ushort_t* Bl = &Bs[w << 9];

    // fragment reads: lane holds row (lane&15), k = (lane>>4)*8 .. +7
    const int frow = lane & 15;
    const int fcol = (lane >> 4) << 3;
    const ushort_t* Afr = &As[(size_t)(wr * FM * 16 + frow) * 32 + fcol];
    const ushort_t* Bfr = &Bs[(size_t)(wc * FN * 16 + frow) * 32 + fcol];

    f32x4 acc[FM][FN];
#pragma unroll
    for (int i = 0; i < FM; ++i)
#pragma unroll
        for (int j = 0; j < FN; ++j) acc[i][j] = (f32x4){0.f, 0.f, 0.f, 0.f};

    for (int k0 = 0; k0 < K; k0 += 32) {
        __syncthreads();   // previous iter's ds_reads done before overwrite
#pragma unroll
        for (int i = 0; i < BM / 64; ++i)
            gload_lds16(Ag + (size_t)i * 64 * K + k0, Al + i * 2048);
#pragma unroll
        for (int i = 0; i < BN / 64; ++i)
            gload_lds16(Bg + (size_t)i * 64 * K + k0, Bl + i * 2048);
        __syncthreads();   // vmcnt(0) drain: staged data visible

        bf16x8 af[FM], bfv[FN];
#pragma unroll
        for (int i = 0; i < FM; ++i) af[i] = *(const bf16x8*)(Afr + i * 512);
#pragma unroll
        for (int j = 0; j < FN; ++j) bfv[j] = *(const bf16x8*)(Bfr + j * 512);
#pragma unroll
        for (int i = 0; i < FM; ++i)
#pragma unroll
            for (int j = 0; j < FN; ++j)
                acc[i][j] = __builtin_amdgcn_mfma_f32_16x16x32_bf16(
                    af[i], bfv[j], acc[i][j], 0, 0, 0);
    }

    // epilogue: C/D layout col=lane&15, row=(lane>>4)*4+r  [m89-verified]
    const int crow0 = m0 + wr * FM * 16 + ((lane >> 4) << 2);
    const int ccol0 = n0 + wc * FN * 16 + (lane & 15);
#pragma unroll
    for (int i = 0; i < FM; ++i)
#pragma unroll
        for (int j = 0; j < FN; ++j)
#pragma unroll
            for (int r = 0; r < 4; ++r) {
                const size_t off = (size_t)(crow0 + i * 16 + r) * N + ccol0 + j * 16;
                float v = acc[i][j][r];
                if (EPI == 1) {
                    const float gg = bf2f(((const ushort_t*)extra)[off]);
                    v *= gg / (1.f + __expf(-gg));
                    ((ushort_t*)Cout)[off] = f2bf_rne(v);
                } else if (EPI == 2) {
                    ((float*)Cout)[off] = v + ((const float*)extra)[off];
                } else if (EPI == 3) {
                    ((ushort_t*)Cout)[off] = f2bf_rne(v);
                } else {
                    ((float*)Cout)[off] = v;
                }
            }
}

// ---------------- product-key routing (unchanged, fp32) ---------------------
__global__ __launch_bounds__(256) void topk_kernel(const float* __restrict__ q,
                                                   const float* __restrict__ keys,
                                                   int* __restrict__ eidx,
                                                   float* __restrict__ ewgt) {
    __shared__ float sim[HEADS][2 * NKEYS];
    __shared__ float comb[HEADS][64];
    __shared__ int   cidx[HEADS][64];
    const int t = blockIdx.x;
    const int head = threadIdx.x >> 6;
    const int lane = threadIdx.x & 63;

#pragma unroll
    for (int i = 0; i < 4; ++i) {
        const int pk = lane + 64 * i;
        const int p = pk >> 7, k = pk & 127;
        const float4* kv = (const float4*)&keys[(size_t)(((head << 7) | k) * 2 + p) * 32];
        const float4* qv = (const float4*)&q[(size_t)t * 256 + p * 128 + head * 32];
        float s = 0.f;
#pragma unroll
        for (int n = 0; n < 8; ++n) {
            const float4 a = qv[n], b = kv[n];
            s += a.x * b.x + a.y * b.y + a.z * b.z + a.w * b.w;
        }
        sim[head][pk] = s;
    }
    __syncthreads();

    if (lane == 0) {
        float sx[TOPK], sy[TOPK];
        int ixx[TOPK], iyy[TOPK];
        float* sp = sim[head];
#pragma unroll
        for (int it = 0; it < TOPK; ++it) {
            float best = -3.4e38f; int bi = 0;
            for (int k = 0; k < NKEYS; ++k)
                if (sp[k] > best) { best = sp[k]; bi = k; }
            sx[it] = best; ixx[it] = bi; sp[bi] = -3.4e38f;
        }
#pragma unroll
        for (int it = 0; it < TOPK; ++it) {
            float best = -3.4e38f; int bi = 0;
            for (int k = 0; k < NKEYS; ++k)
                if (sp[NKEYS + k] > best) { best = sp[NKEYS + k]; bi = k; }
            sy[it] = best; iyy[it] = bi; sp[NKEYS + bi] = -3.4e38f;
        }
#pragma unroll
        for (int a = 0; a < TOPK; ++a)
#pragma unroll
            for (int b = 0; b < TOPK; ++b) {
                comb[head][a * 8 + b] = sx[a] + sy[b];
                cidx[head][a * 8 + b] = ixx[a] * NKEYS + iyy[b];
            }
        float fs[TOPK]; int fi[TOPK];
        float* cp = comb[head];
#pragma unroll
        for (int it = 0; it < TOPK; ++it) {
            float best = -3.4e38f; int bp = 0;
            for (int j = 0; j < 64; ++j)
                if (cp[j] > best) { best = cp[j]; bp = j; }
            fs[it] = best; fi[it] = cidx[head][bp]; cp[bp] = -3.4e38f;
        }
        float m = fs[0];
#pragma unroll
        for (int j = 1; j < TOPK; ++j) m = fmaxf(m, fs[j]);
        float e[TOPK], ssum = 0.f;
#pragma unroll
        for (int j = 0; j < TOPK; ++j) { e[j] = expf(fs[j] - m); ssum += e[j]; }
        const float inv = 1.f / ssum;
#pragma unroll
        for (int j = 0; j < TOPK; ++j) {
            eidx[t * 32 + head * 8 + j] = fi[j];
            ewgt[t * 32 + head * 8 + j] = e[j] * inv;
        }
    }
}

// ---------------- expert gather + weighted accumulate (unchanged) -----------
__global__ __launch_bounds__(256) void experts_kernel(const float* __restrict__ hs,
                                                      const float* __restrict__ down_embed,
                                                      const float* __restrict__ up_embed,
                                                      const int* __restrict__ eidx,
                                                      const float* __restrict__ ewgt,
                                                      float* __restrict__ estate) {
    __shared__ float4 h4[256];
    __shared__ float coeff[32];
    __shared__ int   eid[32];
    __shared__ float wl[32];
    const int t = blockIdx.x;
    const int tid = threadIdx.x;

    h4[tid] = ((const float4*)&hs[(size_t)t * DIM])[tid];
    if (tid < 32) { eid[tid] = eidx[t * 32 + tid]; wl[tid] = ewgt[t * 32 + tid]; }
    __syncthreads();

    const int w = tid >> 6, lane = tid & 63;
#pragma unroll
    for (int jj = 0; jj < 8; ++jj) {
        const int j = w * 8 + jj;
        const int e = eid[j];
        const float4* dr = (const float4*)&down_embed[(size_t)e * DIM];
        float s = 0.f;
#pragma unroll
        for (int c = 0; c < 4; ++c) {
            const float4 a = h4[c * 64 + lane];
            const float4 b = dr[c * 64 + lane];
            s += a.x * b.x + a.y * b.y + a.z * b.z + a.w * b.w;
        }
#pragma unroll
        for (int off = 32; off; off >>= 1) s += __shfl_down(s, off);
        if (lane == 0) coeff[j] = (s / (1.f + expf(-s))) * wl[j];
    }
    __syncthreads();

    float4 acc = {0.f, 0.f, 0.f, 0.f};
#pragma unroll 8
    for (int j = 0; j < 32; ++j) {
        const int e = eid[j];
        const float c = coeff[j];
        const float4 u = *(const float4*)&up_embed[(size_t)e * DIM + (size_t)tid * 4];
        acc.x += c * u.x; acc.y += c * u.y; acc.z += c * u.z; acc.w += c * u.w;
    }
    *(float4*)&estate[(size_t)t * DIM + (size_t)tid * 4] = acc;
}

// ---------------------------------------------------------------------------
extern "C" void kernel_launch(void* const* d_in, const int* in_sizes, int n_in,
                              void* d_out, int out_size, void* d_ws, size_t ws_size,
                              hipStream_t stream) {
    (void)in_sizes; (void)n_in; (void)out_size; (void)ws_size;
    const float* hidden = (const float*)d_in[0];
    const float* wq     = (const float*)d_in[1];
    const float* keys   = (const float*)d_in[2];
    const float* down_e = (const float*)d_in[3];
    const float* up_e   = (const float*)d_in[4];
    const float* wgate  = (const float*)d_in[5];
    const float* wup    = (const float*)d_in[6];
    const float* wdown  = (const float*)d_in[7];
    float* out = (float*)d_out;
    char* ws = (char*)d_ws;

    // workspace layout (bytes); estate(f32,8MB) aliases g(bf16,8MB):
    // g dead after up-GEMM reads it; experts writes estate afterwards.
    ushort_t* hb  = (ushort_t*)(ws);                     // 4 MB
    ushort_t* wqb = (ushort_t*)(ws + (4u << 20));        // 0.5 MB
    ushort_t* wgb = (ushort_t*)(ws + (4608u << 10));     // 4 MB
    ushort_t* wub = (ushort_t*)(ws + (8704u << 10));     // 4 MB
    ushort_t* wdb = (ushort_t*)(ws + (12800u << 10));    // 4 MB
    float*    q   = (float*)   (ws + (16896u << 10));    // 2 MB
    ushort_t* act = (ushort_t*)(ws + (18944u << 10));    // 8 MB
    ushort_t* g   = (ushort_t*)(ws + (27136u << 10));    // 8 MB
    float* estate = (float*)g;                           // alias
    float*    wgt = (float*)   (ws + (35328u << 10));    // 0.25 MB
    int*     eidx = (int*)     (ws + (35584u << 10));    // 0.25 MB  (35.84 MB total)

    // input conversions to bf16
    f32_to_bf16<<<1024, 256, 0, stream>>>(hidden, hb, 262144);
    f32_to_bf16<<<128,  256, 0, stream>>>(wq,     wqb, 32768);
    f32_to_bf16<<<1024, 256, 0, stream>>>(wgate,  wgb, 262144);
    f32_to_bf16<<<1024, 256, 0, stream>>>(wup,    wub, 262144);
    f32_to_bf16<<<1024, 256, 0, stream>>>(wdown,  wdb, 262144);

    // 1) q = hidden @ wq^T  (2048 x 256 x 1024), f32 out for routing
    mfma_gemm<64, 64, 2, 2, 2, 2, 0><<<dim3(4, 32), 256, 0, stream>>>(
        hb, wqb, nullptr, q, TOKENS, 256, DIM);
    // 2) routing
    topk_kernel<<<TOKENS, 256, 0, stream>>>(q, keys, eidx, wgt);
    // 3) g = hidden @ wgate^T -> bf16
    mfma_gemm<128, 128, 2, 2, 4, 4, 3><<<dim3(16, 16), 256, 0, stream>>>(
        hb, wgb, nullptr, g, TOKENS, INTER, DIM);
    // 4) act = silu(g) * (hidden @ wup^T) -> bf16
    mfma_gemm<128, 128, 2, 2, 4, 4, 1><<<dim3(16, 16), 256, 0, stream>>>(
        hb, wub, g, act, TOKENS, INTER, DIM);
    // 5) experts (writes estate over dead g)
    experts_kernel<<<TOKENS, 256, 0, stream>>>(hidden, down_e, up_e, eidx, wgt, estate);
    // 6) out = act @ wdown^T + estate  (2048 x 1024 x 2048)
    mfma_gemm<64, 128, 1, 4, 4, 2, 2><<<dim3(8, 32), 256, 0, stream>>>(
        act, wdb, estate, out, TOKENS, DIM, INTER);
}

// Round 3
// 247.914 us; speedup vs baseline: 2.6939x; 1.4010x over previous
//
#include <hip/hip_runtime.h>
#include <hip/hip_bf16.h>
#include <math.h>

// ---------------------------------------------------------------------------
// DogeCDMoE round 3: wave-parallel product-key top-k (butterfly shfl_xor
// max-extraction, register-resident sims) replacing the serial lane-0 scan.
// bf16 MFMA GEMMs and experts kernel unchanged from the passing round 2.
// ---------------------------------------------------------------------------

#define TOKENS 2048
#define DIM    1024
#define INTER  2048
#define NKEYS  128
#define TOPK   8
#define HEADS  4
#define NINF  -3.4e38f

typedef unsigned short ushort_t;
typedef __attribute__((ext_vector_type(8))) short bf16x8;
typedef __attribute__((ext_vector_type(4))) float f32x4;

__device__ __forceinline__ float bf2f(ushort_t u) {
    unsigned int x = (unsigned int)u << 16;
    float f; __builtin_memcpy(&f, &x, 4); return f;
}
__device__ __forceinline__ ushort_t f2bf_rne(float f) {
    unsigned int x; __builtin_memcpy(&x, &f, 4);
    x += 0x7fffu + ((x >> 16) & 1u);
    return (ushort_t)(x >> 16);
}
__device__ __forceinline__ void gload_lds16(const void* g, void* l) {
    __builtin_amdgcn_global_load_lds(
        (const __attribute__((address_space(1))) unsigned int*)g,
        (__attribute__((address_space(3))) unsigned int*)l, 16, 0, 0);
}

// ---------------- fused f32 -> bf16 (RNE) for all 5 tensors -----------------
// chunk = 8 elems. bounds: hidden 262144 | wq 32768 | wgate/wup/wdown 262144
__global__ __launch_bounds__(256) void convert_all(
    const float* __restrict__ h,  const float* __restrict__ wq,
    const float* __restrict__ wg, const float* __restrict__ wu,
    const float* __restrict__ wd,
    ushort_t* __restrict__ hb,  ushort_t* __restrict__ wqb,
    ushort_t* __restrict__ wgb, ushort_t* __restrict__ wub,
    ushort_t* __restrict__ wdb) {
    const int i = blockIdx.x * 256 + threadIdx.x;
    const float* src; ushort_t* dst; int off;
    if      (i <  262144) { src = h;  dst = hb;  off = i; }
    else if (i <  294912) { src = wq; dst = wqb; off = i - 262144; }
    else if (i <  557056) { src = wg; dst = wgb; off = i - 294912; }
    else if (i <  819200) { src = wu; dst = wub; off = i - 557056; }
    else                  { src = wd; dst = wdb; off = i - 819200; }
    const float4* p = (const float4*)src + (size_t)off * 2;
    const float4 a = p[0], b = p[1];
    uint4 o;
    o.x = (unsigned)f2bf_rne(a.x) | ((unsigned)f2bf_rne(a.y) << 16);
    o.y = (unsigned)f2bf_rne(a.z) | ((unsigned)f2bf_rne(a.w) << 16);
    o.z = (unsigned)f2bf_rne(b.x) | ((unsigned)f2bf_rne(b.y) << 16);
    o.w = (unsigned)f2bf_rne(b.z) | ((unsigned)f2bf_rne(b.w) << 16);
    ((uint4*)dst)[off] = o;
}

// ---------------- bf16 MFMA GEMM: C[M,N] = A[M,K] @ B[N,K]^T ----------------
// EPI 0: Cout f32 = acc
// EPI 1: Cout bf16 = silu(extra_bf16) * acc      (up-proj: act = silu(g)*up)
// EPI 2: Cout f32 = acc + extra_f32              (down-proj + experts add)
// EPI 3: Cout bf16 = acc                         (gate-proj)
template<int BM, int BN, int WR, int WC, int FM, int FN, int EPI>
__global__ __launch_bounds__(256) void mfma_gemm(const ushort_t* __restrict__ A,
                                                 const ushort_t* __restrict__ B,
                                                 const void* __restrict__ extra,
                                                 void* __restrict__ Cout,
                                                 int M, int N, int K) {
    static_assert(WR * WC == 4 && WR * FM * 16 == BM && WC * FN * 16 == BN, "geom");
    __shared__ ushort_t As[BM * 32];
    __shared__ ushort_t Bs[BN * 32];
    const int tid = threadIdx.x;
    const int w = tid >> 6, lane = tid & 63;
    const int wr = w / WC, wc = w % WC;
    const int m0 = blockIdx.y * BM, n0 = blockIdx.x * BN;

    const int srow = (w << 4) + (lane >> 2);
    const int scol = (lane & 3) << 3;
    const ushort_t* Ag = &A[(size_t)(m0 + srow) * K + scol];
    const ushort_t* Bg = &B[(size_t)(n0 + srow) * K + scol];
    ushort_t* Al = &As[w << 9];
    ushort_t* Bl = &Bs[w << 9];

    const int frow = lane & 15;
    const int fcol = (lane >> 4) << 3;
    const ushort_t* Afr = &As[(size_t)(wr * FM * 16 + frow) * 32 + fcol];
    const ushort_t* Bfr = &Bs[(size_t)(wc * FN * 16 + frow) * 32 + fcol];

    f32x4 acc[FM][FN];
#pragma unroll
    for (int i = 0; i < FM; ++i)
#pragma unroll
        for (int j = 0; j < FN; ++j) acc[i][j] = (f32x4){0.f, 0.f, 0.f, 0.f};

    for (int k0 = 0; k0 < K; k0 += 32) {
        __syncthreads();
#pragma unroll
        for (int i = 0; i < BM / 64; ++i)
            gload_lds16(Ag + (size_t)i * 64 * K + k0, Al + i * 2048);
#pragma unroll
        for (int i = 0; i < BN / 64; ++i)
            gload_lds16(Bg + (size_t)i * 64 * K + k0, Bl + i * 2048);
        __syncthreads();

        bf16x8 af[FM], bfv[FN];
#pragma unroll
        for (int i = 0; i < FM; ++i) af[i] = *(const bf16x8*)(Afr + i * 512);
#pragma unroll
        for (int j = 0; j < FN; ++j) bfv[j] = *(const bf16x8*)(Bfr + j * 512);
#pragma unroll
        for (int i = 0; i < FM; ++i)
#pragma unroll
            for (int j = 0; j < FN; ++j)
                acc[i][j] = __builtin_amdgcn_mfma_f32_16x16x32_bf16(
                    af[i], bfv[j], acc[i][j], 0, 0, 0);
    }

    const int crow0 = m0 + wr * FM * 16 + ((lane >> 4) << 2);
    const int ccol0 = n0 + wc * FN * 16 + (lane & 15);
#pragma unroll
    for (int i = 0; i < FM; ++i)
#pragma unroll
        for (int j = 0; j < FN; ++j)
#pragma unroll
            for (int r = 0; r < 4; ++r) {
                const size_t off = (size_t)(crow0 + i * 16 + r) * N + ccol0 + j * 16;
                float v = acc[i][j][r];
                if (EPI == 1) {
                    const float gg = bf2f(((const ushort_t*)extra)[off]);
                    v *= gg / (1.f + __expf(-gg));
                    ((ushort_t*)Cout)[off] = f2bf_rne(v);
                } else if (EPI == 2) {
                    ((float*)Cout)[off] = v + ((const float*)extra)[off];
                } else if (EPI == 3) {
                    ((ushort_t*)Cout)[off] = f2bf_rne(v);
                } else {
                    ((float*)Cout)[off] = v;
                }
            }
}

// ---------------- wave-parallel product-key routing --------------------------
// One wave per (token, head). Sims register-resident: lane owns keys
// {2*lane, 2*lane+1} of each codebook. Top-8 via butterfly max-extract with
// jax.lax.top_k tie order (min index / min position on equal values).
__global__ __launch_bounds__(256) void topk_kernel(const float* __restrict__ q,
                                                   const float* __restrict__ keys,
                                                   int* __restrict__ eidx,
                                                   float* __restrict__ ewgt) {
    const int t = blockIdx.x;
    const int head = threadIdx.x >> 6;
    const int lane = threadIdx.x & 63;

    // q halves for this head (32 floats each), broadcast-cached loads
    const float4* qx = (const float4*)&q[(size_t)t * 256 + head * 32];
    const float4* qy = (const float4*)&q[(size_t)t * 256 + 128 + head * 32];
    float4 qxv[8], qyv[8];
#pragma unroll
    for (int n = 0; n < 8; ++n) { qxv[n] = qx[n]; qyv[n] = qy[n]; }

    // per-lane sim candidates
    float cx0, cx1, cy0, cy1;
    {
        float s[4];
#pragma unroll
        for (int j = 0; j < 2; ++j) {
            const int k = 2 * lane + j;
            const float4* kx = (const float4*)&keys[(size_t)(((head << 7) | k) * 2 + 0) * 32];
            const float4* ky = (const float4*)&keys[(size_t)(((head << 7) | k) * 2 + 1) * 32];
            float sx = 0.f, sy = 0.f;
#pragma unroll
            for (int n = 0; n < 8; ++n) {
                const float4 a = qxv[n], b = kx[n];
                sx += a.x * b.x + a.y * b.y + a.z * b.z + a.w * b.w;
                const float4 c = qyv[n], d = ky[n];
                sy += c.x * d.x + c.y * d.y + c.z * d.z + c.w * d.w;
            }
            s[j * 2] = sx; s[j * 2 + 1] = sy;
        }
        cx0 = s[0]; cy0 = s[1]; cx1 = s[2]; cy1 = s[3];
    }

    // --- top-8 of 128 (x codebook), winners distributed to lanes 0..7 ---
    float sx_mine = NINF, sy_mine = NINF;
    int sxi_mine = 0, syi_mine = 0;
    {
        float c0 = cx0, c1 = cx1;
#pragma unroll
        for (int it = 0; it < TOPK; ++it) {
            float bv; int bi;
            if (c1 > c0) { bv = c1; bi = 2 * lane + 1; } else { bv = c0; bi = 2 * lane; }
#pragma unroll
            for (int m = 1; m < 64; m <<= 1) {
                const float ov = __shfl_xor(bv, m);
                const int   oi = __shfl_xor(bi, m);
                if (ov > bv || (ov == bv && oi < bi)) { bv = ov; bi = oi; }
            }
            if (lane == it) { sx_mine = bv; sxi_mine = bi; }
            if (bi == 2 * lane) c0 = NINF;
            else if (bi == 2 * lane + 1) c1 = NINF;
        }
    }
    // --- top-8 of 128 (y codebook) ---
    {
        float c0 = cy0, c1 = cy1;
#pragma unroll
        for (int it = 0; it < TOPK; ++it) {
            float bv; int bi;
            if (c1 > c0) { bv = c1; bi = 2 * lane + 1; } else { bv = c0; bi = 2 * lane; }
#pragma unroll
            for (int m = 1; m < 64; m <<= 1) {
                const float ov = __shfl_xor(bv, m);
                const int   oi = __shfl_xor(bi, m);
                if (ov > bv || (ov == bv && oi < bi)) { bv = ov; bi = oi; }
            }
            if (lane == it) { sy_mine = bv; syi_mine = bi; }
            if (bi == 2 * lane) c0 = NINF;
            else if (bi == 2 * lane + 1) c1 = NINF;
        }
    }

    // --- cartesian combine on 64 lanes: a = lane>>3, b = lane&7 ---
    const float sa = __shfl(sx_mine, lane >> 3);
    const int   ia = __shfl(sxi_mine, lane >> 3);
    const float sb = __shfl(sy_mine, lane & 7);
    const int   ib = __shfl(syi_mine, lane & 7);
    float cv = sa + sb;
    const int ci = ia * NKEYS + ib;

    // --- top-8 of 64, tie -> lower position (position == lane == a*8+b) ---
    float fs_mine = NINF; int fi_mine = 0;
#pragma unroll
    for (int it = 0; it < TOPK; ++it) {
        float bv = cv; int bp = lane; int bx = ci;
#pragma unroll
        for (int m = 1; m < 64; m <<= 1) {
            const float ov = __shfl_xor(bv, m);
            const int   op = __shfl_xor(bp, m);
            const int   ox = __shfl_xor(bx, m);
            if (ov > bv || (ov == bv && op < bp)) { bv = ov; bp = op; bx = ox; }
        }
        if (lane == it) { fs_mine = bv; fi_mine = bx; }
        if (lane == bp) cv = NINF;
    }

    // --- softmax over the 8 winners (distributed on lanes 0..7) ---
    float f[8];
#pragma unroll
    for (int j = 0; j < 8; ++j) f[j] = __shfl(fs_mine, j);
    float mx = f[0];
#pragma unroll
    for (int j = 1; j < 8; ++j) mx = fmaxf(mx, f[j]);
    float ssum = 0.f;
#pragma unroll
    for (int j = 0; j < 8; ++j) ssum += expf(f[j] - mx);
    if (lane < 8) {
        eidx[t * 32 + head * 8 + lane] = fi_mine;
        ewgt[t * 32 + head * 8 + lane] = expf(fs_mine - mx) / ssum;
    }
}

// ---------------- expert gather + weighted accumulate (unchanged) -----------
__global__ __launch_bounds__(256) void experts_kernel(const float* __restrict__ hs,
                                                      const float* __restrict__ down_embed,
                                                      const float* __restrict__ up_embed,
                                                      const int* __restrict__ eidx,
                                                      const float* __restrict__ ewgt,
                                                      float* __restrict__ estate) {
    __shared__ float4 h4[256];
    __shared__ float coeff[32];
    __shared__ int   eid[32];
    __shared__ float wl[32];
    const int t = blockIdx.x;
    const int tid = threadIdx.x;

    h4[tid] = ((const float4*)&hs[(size_t)t * DIM])[tid];
    if (tid < 32) { eid[tid] = eidx[t * 32 + tid]; wl[tid] = ewgt[t * 32 + tid]; }
    __syncthreads();

    const int w = tid >> 6, lane = tid & 63;
#pragma unroll
    for (int jj = 0; jj < 8; ++jj) {
        const int j = w * 8 + jj;
        const int e = eid[j];
        const float4* dr = (const float4*)&down_embed[(size_t)e * DIM];
        float s = 0.f;
#pragma unroll
        for (int c = 0; c < 4; ++c) {
            const float4 a = h4[c * 64 + lane];
            const float4 b = dr[c * 64 + lane];
            s += a.x * b.x + a.y * b.y + a.z * b.z + a.w * b.w;
        }
#pragma unroll
        for (int off = 32; off; off >>= 1) s += __shfl_down(s, off);
        if (lane == 0) coeff[j] = (s / (1.f + expf(-s))) * wl[j];
    }
    __syncthreads();

    float4 acc = {0.f, 0.f, 0.f, 0.f};
#pragma unroll 8
    for (int j = 0; j < 32; ++j) {
        const int e = eid[j];
        const float c = coeff[j];
        const float4 u = *(const float4*)&up_embed[(size_t)e * DIM + (size_t)tid * 4];
        acc.x += c * u.x; acc.y += c * u.y; acc.z += c * u.z; acc.w += c * u.w;
    }
    *(float4*)&estate[(size_t)t * DIM + (size_t)tid * 4] = acc;
}

// ---------------------------------------------------------------------------
extern "C" void kernel_launch(void* const* d_in, const int* in_sizes, int n_in,
                              void* d_out, int out_size, void* d_ws, size_t ws_size,
                              hipStream_t stream) {
    (void)in_sizes; (void)n_in; (void)out_size; (void)ws_size;
    const float* hidden = (const float*)d_in[0];
    const float* wq     = (const float*)d_in[1];
    const float* keys   = (const float*)d_in[2];
    const float* down_e = (const float*)d_in[3];
    const float* up_e   = (const float*)d_in[4];
    const float* wgate  = (const float*)d_in[5];
    const float* wup    = (const float*)d_in[6];
    const float* wdown  = (const float*)d_in[7];
    float* out = (float*)d_out;
    char* ws = (char*)d_ws;

    // workspace layout (bytes); estate(f32,8MB) aliases g(bf16,8MB):
    // g dead after up-GEMM reads it; experts writes estate afterwards.
    ushort_t* hb  = (ushort_t*)(ws);                     // 4 MB
    ushort_t* wqb = (ushort_t*)(ws + (4u << 20));        // 0.5 MB
    ushort_t* wgb = (ushort_t*)(ws + (4608u << 10));     // 4 MB
    ushort_t* wub = (ushort_t*)(ws + (8704u << 10));     // 4 MB
    ushort_t* wdb = (ushort_t*)(ws + (12800u << 10));    // 4 MB
    float*    q   = (float*)   (ws + (16896u << 10));    // 2 MB
    ushort_t* act = (ushort_t*)(ws + (18944u << 10));    // 8 MB
    ushort_t* g   = (ushort_t*)(ws + (27136u << 10));    // 8 MB
    float* estate = (float*)g;                           // alias
    float*    wgt = (float*)   (ws + (35328u << 10));    // 0.25 MB
    int*     eidx = (int*)     (ws + (35584u << 10));    // 0.25 MB

    // all f32->bf16 conversions in one launch (4224 * 256 * 8 elems)
    convert_all<<<4224, 256, 0, stream>>>(hidden, wq, wgate, wup, wdown,
                                          hb, wqb, wgb, wub, wdb);

    // 1) q = hidden @ wq^T  (2048 x 256 x 1024), f32 out for routing
    mfma_gemm<64, 64, 2, 2, 2, 2, 0><<<dim3(4, 32), 256, 0, stream>>>(
        hb, wqb, nullptr, q, TOKENS, 256, DIM);
    // 2) routing (wave-parallel)
    topk_kernel<<<TOKENS, 256, 0, stream>>>(q, keys, eidx, wgt);
    // 3) g = hidden @ wgate^T -> bf16
    mfma_gemm<128, 128, 2, 2, 4, 4, 3><<<dim3(16, 16), 256, 0, stream>>>(
        hb, wgb, nullptr, g, TOKENS, INTER, DIM);
    // 4) act = silu(g) * (hidden @ wup^T) -> bf16
    mfma_gemm<128, 128, 2, 2, 4, 4, 1><<<dim3(16, 16), 256, 0, stream>>>(
        hb, wub, g, act, TOKENS, INTER, DIM);
    // 5) experts (writes estate over dead g)
    experts_kernel<<<TOKENS, 256, 0, stream>>>(hidden, down_e, up_e, eidx, wgt, estate);
    // 6) out = act @ wdown^T + estate  (2048 x 1024 x 2048)
    mfma_gemm<64, 128, 1, 4, 4, 2, 2><<<dim3(8, 32), 256, 0, stream>>>(
        act, wdb, estate, out, TOKENS, DIM, INTER);
}

// Round 4
// 246.623 us; speedup vs baseline: 2.7080x; 1.0052x over previous
//
#include <hip/hip_runtime.h>
#include <hip/hip_bf16.h>
#include <math.h>

// ---------------------------------------------------------------------------
// DogeCDMoE round 4: experts_kernel restructured for memory-level parallelism
// (fused de-dot + ue-accumulate per wave, 1-deep software pipeline, register-
// resident hidden/acc slices, single cross-wave LDS reduce). Round-3 kernel
// was latency-bound at VGPR=32 (compiler-throttled ILP, 38% HBM).
// Everything else unchanged from the passing round 3.
// ---------------------------------------------------------------------------

#define TOKENS 2048
#define DIM    1024
#define INTER  2048
#define NKEYS  128
#define TOPK   8
#define HEADS  4
#define NINF  -3.4e38f

typedef unsigned short ushort_t;
typedef __attribute__((ext_vector_type(8))) short bf16x8;
typedef __attribute__((ext_vector_type(4))) float f32x4;

__device__ __forceinline__ float bf2f(ushort_t u) {
    unsigned int x = (unsigned int)u << 16;
    float f; __builtin_memcpy(&f, &x, 4); return f;
}
__device__ __forceinline__ ushort_t f2bf_rne(float f) {
    unsigned int x; __builtin_memcpy(&x, &f, 4);
    x += 0x7fffu + ((x >> 16) & 1u);
    return (ushort_t)(x >> 16);
}
__device__ __forceinline__ void gload_lds16(const void* g, void* l) {
    __builtin_amdgcn_global_load_lds(
        (const __attribute__((address_space(1))) unsigned int*)g,
        (__attribute__((address_space(3))) unsigned int*)l, 16, 0, 0);
}

// ---------------- fused f32 -> bf16 (RNE) for all 5 tensors -----------------
__global__ __launch_bounds__(256) void convert_all(
    const float* __restrict__ h,  const float* __restrict__ wq,
    const float* __restrict__ wg, const float* __restrict__ wu,
    const float* __restrict__ wd,
    ushort_t* __restrict__ hb,  ushort_t* __restrict__ wqb,
    ushort_t* __restrict__ wgb, ushort_t* __restrict__ wub,
    ushort_t* __restrict__ wdb) {
    const int i = blockIdx.x * 256 + threadIdx.x;
    const float* src; ushort_t* dst; int off;
    if      (i <  262144) { src = h;  dst = hb;  off = i; }
    else if (i <  294912) { src = wq; dst = wqb; off = i - 262144; }
    else if (i <  557056) { src = wg; dst = wgb; off = i - 294912; }
    else if (i <  819200) { src = wu; dst = wub; off = i - 557056; }
    else                  { src = wd; dst = wdb; off = i - 819200; }
    const float4* p = (const float4*)src + (size_t)off * 2;
    const float4 a = p[0], b = p[1];
    uint4 o;
    o.x = (unsigned)f2bf_rne(a.x) | ((unsigned)f2bf_rne(a.y) << 16);
    o.y = (unsigned)f2bf_rne(a.z) | ((unsigned)f2bf_rne(a.w) << 16);
    o.z = (unsigned)f2bf_rne(b.x) | ((unsigned)f2bf_rne(b.y) << 16);
    o.w = (unsigned)f2bf_rne(b.z) | ((unsigned)f2bf_rne(b.w) << 16);
    ((uint4*)dst)[off] = o;
}

// ---------------- bf16 MFMA GEMM: C[M,N] = A[M,K] @ B[N,K]^T ----------------
// EPI 0: f32 = acc | 1: bf16 = silu(extra_bf16)*acc | 2: f32 = acc+extra_f32
// EPI 3: bf16 = acc
template<int BM, int BN, int WR, int WC, int FM, int FN, int EPI>
__global__ __launch_bounds__(256) void mfma_gemm(const ushort_t* __restrict__ A,
                                                 const ushort_t* __restrict__ B,
                                                 const void* __restrict__ extra,
                                                 void* __restrict__ Cout,
                                                 int M, int N, int K) {
    static_assert(WR * WC == 4 && WR * FM * 16 == BM && WC * FN * 16 == BN, "geom");
    __shared__ ushort_t As[BM * 32];
    __shared__ ushort_t Bs[BN * 32];
    const int tid = threadIdx.x;
    const int w = tid >> 6, lane = tid & 63;
    const int wr = w / WC, wc = w % WC;
    const int m0 = blockIdx.y * BM, n0 = blockIdx.x * BN;

    const int srow = (w << 4) + (lane >> 2);
    const int scol = (lane & 3) << 3;
    const ushort_t* Ag = &A[(size_t)(m0 + srow) * K + scol];
    const ushort_t* Bg = &B[(size_t)(n0 + srow) * K + scol];
    ushort_t* Al = &As[w << 9];
    ushort_t* Bl = &Bs[w << 9];

    const int frow = lane & 15;
    const int fcol = (lane >> 4) << 3;
    const ushort_t* Afr = &As[(size_t)(wr * FM * 16 + frow) * 32 + fcol];
    const ushort_t* Bfr = &Bs[(size_t)(wc * FN * 16 + frow) * 32 + fcol];

    f32x4 acc[FM][FN];
#pragma unroll
    for (int i = 0; i < FM; ++i)
#pragma unroll
        for (int j = 0; j < FN; ++j) acc[i][j] = (f32x4){0.f, 0.f, 0.f, 0.f};

    for (int k0 = 0; k0 < K; k0 += 32) {
        __syncthreads();
#pragma unroll
        for (int i = 0; i < BM / 64; ++i)
            gload_lds16(Ag + (size_t)i * 64 * K + k0, Al + i * 2048);
#pragma unroll
        for (int i = 0; i < BN / 64; ++i)
            gload_lds16(Bg + (size_t)i * 64 * K + k0, Bl + i * 2048);
        __syncthreads();

        bf16x8 af[FM], bfv[FN];
#pragma unroll
        for (int i = 0; i < FM; ++i) af[i] = *(const bf16x8*)(Afr + i * 512);
#pragma unroll
        for (int j = 0; j < FN; ++j) bfv[j] = *(const bf16x8*)(Bfr + j * 512);
#pragma unroll
        for (int i = 0; i < FM; ++i)
#pragma unroll
            for (int j = 0; j < FN; ++j)
                acc[i][j] = __builtin_amdgcn_mfma_f32_16x16x32_bf16(
                    af[i], bfv[j], acc[i][j], 0, 0, 0);
    }

    const int crow0 = m0 + wr * FM * 16 + ((lane >> 4) << 2);
    const int ccol0 = n0 + wc * FN * 16 + (lane & 15);
#pragma unroll
    for (int i = 0; i < FM; ++i)
#pragma unroll
        for (int j = 0; j < FN; ++j)
#pragma unroll
            for (int r = 0; r < 4; ++r) {
                const size_t off = (size_t)(crow0 + i * 16 + r) * N + ccol0 + j * 16;
                float v = acc[i][j][r];
                if (EPI == 1) {
                    const float gg = bf2f(((const ushort_t*)extra)[off]);
                    v *= gg / (1.f + __expf(-gg));
                    ((ushort_t*)Cout)[off] = f2bf_rne(v);
                } else if (EPI == 2) {
                    ((float*)Cout)[off] = v + ((const float*)extra)[off];
                } else if (EPI == 3) {
                    ((ushort_t*)Cout)[off] = f2bf_rne(v);
                } else {
                    ((float*)Cout)[off] = v;
                }
            }
}

// ---------------- wave-parallel product-key routing (unchanged) --------------
__global__ __launch_bounds__(256) void topk_kernel(const float* __restrict__ q,
                                                   const float* __restrict__ keys,
                                                   int* __restrict__ eidx,
                                                   float* __restrict__ ewgt) {
    const int t = blockIdx.x;
    const int head = threadIdx.x >> 6;
    const int lane = threadIdx.x & 63;

    const float4* qx = (const float4*)&q[(size_t)t * 256 + head * 32];
    const float4* qy = (const float4*)&q[(size_t)t * 256 + 128 + head * 32];
    float4 qxv[8], qyv[8];
#pragma unroll
    for (int n = 0; n < 8; ++n) { qxv[n] = qx[n]; qyv[n] = qy[n]; }

    float cx0, cx1, cy0, cy1;
    {
        float s[4];
#pragma unroll
        for (int j = 0; j < 2; ++j) {
            const int k = 2 * lane + j;
            const float4* kx = (const float4*)&keys[(size_t)(((head << 7) | k) * 2 + 0) * 32];
            const float4* ky = (const float4*)&keys[(size_t)(((head << 7) | k) * 2 + 1) * 32];
            float sx = 0.f, sy = 0.f;
#pragma unroll
            for (int n = 0; n < 8; ++n) {
                const float4 a = qxv[n], b = kx[n];
                sx += a.x * b.x + a.y * b.y + a.z * b.z + a.w * b.w;
                const float4 c = qyv[n], d = ky[n];
                sy += c.x * d.x + c.y * d.y + c.z * d.z + c.w * d.w;
            }
            s[j * 2] = sx; s[j * 2 + 1] = sy;
        }
        cx0 = s[0]; cy0 = s[1]; cx1 = s[2]; cy1 = s[3];
    }

    float sx_mine = NINF, sy_mine = NINF;
    int sxi_mine = 0, syi_mine = 0;
    {
        float c0 = cx0, c1 = cx1;
#pragma unroll
        for (int it = 0; it < TOPK; ++it) {
            float bv; int bi;
            if (c1 > c0) { bv = c1; bi = 2 * lane + 1; } else { bv = c0; bi = 2 * lane; }
#pragma unroll
            for (int m = 1; m < 64; m <<= 1) {
                const float ov = __shfl_xor(bv, m);
                const int   oi = __shfl_xor(bi, m);
                if (ov > bv || (ov == bv && oi < bi)) { bv = ov; bi = oi; }
            }
            if (lane == it) { sx_mine = bv; sxi_mine = bi; }
            if (bi == 2 * lane) c0 = NINF;
            else if (bi == 2 * lane + 1) c1 = NINF;
        }
    }
    {
        float c0 = cy0, c1 = cy1;
#pragma unroll
        for (int it = 0; it < TOPK; ++it) {
            float bv; int bi;
            if (c1 > c0) { bv = c1; bi = 2 * lane + 1; } else { bv = c0; bi = 2 * lane; }
#pragma unroll
            for (int m = 1; m < 64; m <<= 1) {
                const float ov = __shfl_xor(bv, m);
                const int   oi = __shfl_xor(bi, m);
                if (ov > bv || (ov == bv && oi < bi)) { bv = ov; bi = oi; }
            }
            if (lane == it) { sy_mine = bv; syi_mine = bi; }
            if (bi == 2 * lane) c0 = NINF;
            else if (bi == 2 * lane + 1) c1 = NINF;
        }
    }

    const float sa = __shfl(sx_mine, lane >> 3);
    const int   ia = __shfl(sxi_mine, lane >> 3);
    const float sb = __shfl(sy_mine, lane & 7);
    const int   ib = __shfl(syi_mine, lane & 7);
    float cv = sa + sb;
    const int ci = ia * NKEYS + ib;

    float fs_mine = NINF; int fi_mine = 0;
#pragma unroll
    for (int it = 0; it < TOPK; ++it) {
        float bv = cv; int bp = lane; int bx = ci;
#pragma unroll
        for (int m = 1; m < 64; m <<= 1) {
            const float ov = __shfl_xor(bv, m);
            const int   op = __shfl_xor(bp, m);
            const int   ox = __shfl_xor(bx, m);
            if (ov > bv || (ov == bv && op < bp)) { bv = ov; bp = op; bx = ox; }
        }
        if (lane == it) { fs_mine = bv; fi_mine = bx; }
        if (lane == bp) cv = NINF;
    }

    float f[8];
#pragma unroll
    for (int j = 0; j < 8; ++j) f[j] = __shfl(fs_mine, j);
    float mx = f[0];
#pragma unroll
    for (int j = 1; j < 8; ++j) mx = fmaxf(mx, f[j]);
    float ssum = 0.f;
#pragma unroll
    for (int j = 0; j < 8; ++j) ssum += expf(f[j] - mx);
    if (lane < 8) {
        eidx[t * 32 + head * 8 + lane] = fi_mine;
        ewgt[t * 32 + head * 8 + lane] = expf(fs_mine - mx) / ssum;
    }
}

// ---------------- experts: fused gather-dot-accumulate, deep MLP ------------
// One block per token; wave w owns experts w*8..w*8+7 end-to-end:
//   coeff_j = silu(h . de[e_j]) * wgt_j ; acc += coeff_j * ue[e_j]
// Lane owns float4 chunks {lane, lane+64, lane+128, lane+192} of the 1024-dim
// row (coalesced); butterfly-xor reduce gives the dot to all lanes (identical
// rounding across lanes). 1-deep prefetch keeps 8 float4 loads in flight.
// Final cross-wave sum via conflict-free LDS float4 tiles.
__global__ __launch_bounds__(256) void experts_kernel(const float* __restrict__ hs,
                                                      const float* __restrict__ down_embed,
                                                      const float* __restrict__ up_embed,
                                                      const int* __restrict__ eidx,
                                                      const float* __restrict__ ewgt,
                                                      float* __restrict__ estate) {
    __shared__ float4 partial[4][256];
    __shared__ int   eid[32];
    __shared__ float wl[32];
    const int t = blockIdx.x;
    const int tid = threadIdx.x;
    const int w = tid >> 6, lane = tid & 63;

    if (tid < 32) { eid[tid] = eidx[t * 32 + tid]; wl[tid] = ewgt[t * 32 + tid]; }

    const float4* hs4 = (const float4*)hs + (size_t)t * 256;
    float4 h[4];
#pragma unroll
    for (int i = 0; i < 4; ++i) h[i] = hs4[i * 64 + lane];

    const float4* de4 = (const float4*)down_embed;
    const float4* ue4 = (const float4*)up_embed;
    __syncthreads();

    float4 acc[4];
#pragma unroll
    for (int i = 0; i < 4; ++i) acc[i] = (float4){0.f, 0.f, 0.f, 0.f};

    float4 d[4], u[4], nd[4], nu[4];
    {
        const size_t b = (size_t)eid[w * 8] * 256;
#pragma unroll
        for (int i = 0; i < 4; ++i) { d[i] = de4[b + i * 64 + lane]; u[i] = ue4[b + i * 64 + lane]; }
    }
#pragma unroll
    for (int jj = 0; jj < 8; ++jj) {
        if (jj < 7) {   // prefetch next expert's rows before the reduce chain
            const size_t b = (size_t)eid[w * 8 + jj + 1] * 256;
#pragma unroll
            for (int i = 0; i < 4; ++i) { nd[i] = de4[b + i * 64 + lane]; nu[i] = ue4[b + i * 64 + lane]; }
        }
        float s = 0.f;
#pragma unroll
        for (int i = 0; i < 4; ++i)
            s += h[i].x * d[i].x + h[i].y * d[i].y + h[i].z * d[i].z + h[i].w * d[i].w;
#pragma unroll
        for (int m = 1; m < 64; m <<= 1) s += __shfl_xor(s, m);
        const float c = (s / (1.f + __expf(-s))) * wl[w * 8 + jj];
#pragma unroll
        for (int i = 0; i < 4; ++i) {
            acc[i].x += c * u[i].x; acc[i].y += c * u[i].y;
            acc[i].z += c * u[i].z; acc[i].w += c * u[i].w;
        }
        if (jj < 7) {
#pragma unroll
            for (int i = 0; i < 4; ++i) { d[i] = nd[i]; u[i] = nu[i]; }
        }
    }

#pragma unroll
    for (int i = 0; i < 4; ++i) partial[w][i * 64 + lane] = acc[i];
    __syncthreads();

    // thread tid owns output chunk tid: sum the 4 wave partials
    const float4 p0 = partial[0][tid], p1 = partial[1][tid];
    const float4 p2 = partial[2][tid], p3 = partial[3][tid];
    float4 o;
    o.x = p0.x + p1.x + p2.x + p3.x;
    o.y = p0.y + p1.y + p2.y + p3.y;
    o.z = p0.z + p1.z + p2.z + p3.z;
    o.w = p0.w + p1.w + p2.w + p3.w;
    ((float4*)estate)[(size_t)t * 256 + tid] = o;
}

// ---------------------------------------------------------------------------
extern "C" void kernel_launch(void* const* d_in, const int* in_sizes, int n_in,
                              void* d_out, int out_size, void* d_ws, size_t ws_size,
                              hipStream_t stream) {
    (void)in_sizes; (void)n_in; (void)out_size; (void)ws_size;
    const float* hidden = (const float*)d_in[0];
    const float* wq     = (const float*)d_in[1];
    const float* keys   = (const float*)d_in[2];
    const float* down_e = (const float*)d_in[3];
    const float* up_e   = (const float*)d_in[4];
    const float* wgate  = (const float*)d_in[5];
    const float* wup    = (const float*)d_in[6];
    const float* wdown  = (const float*)d_in[7];
    float* out = (float*)d_out;
    char* ws = (char*)d_ws;

    // workspace layout (bytes); estate(f32,8MB) aliases g(bf16,8MB):
    // g dead after up-GEMM reads it; experts writes estate afterwards.
    ushort_t* hb  = (ushort_t*)(ws);                     // 4 MB
    ushort_t* wqb = (ushort_t*)(ws + (4u << 20));        // 0.5 MB
    ushort_t* wgb = (ushort_t*)(ws + (4608u << 10));     // 4 MB
    ushort_t* wub = (ushort_t*)(ws + (8704u << 10));     // 4 MB
    ushort_t* wdb = (ushort_t*)(ws + (12800u << 10));    // 4 MB
    float*    q   = (float*)   (ws + (16896u << 10));    // 2 MB
    ushort_t* act = (ushort_t*)(ws + (18944u << 10));    // 8 MB
    ushort_t* g   = (ushort_t*)(ws + (27136u << 10));    // 8 MB
    float* estate = (float*)g;                           // alias
    float*    wgt = (float*)   (ws + (35328u << 10));    // 0.25 MB
    int*     eidx = (int*)     (ws + (35584u << 10));    // 0.25 MB

    convert_all<<<4224, 256, 0, stream>>>(hidden, wq, wgate, wup, wdown,
                                          hb, wqb, wgb, wub, wdb);

    // 1) q = hidden @ wq^T  (2048 x 256 x 1024), f32 out for routing
    mfma_gemm<64, 64, 2, 2, 2, 2, 0><<<dim3(4, 32), 256, 0, stream>>>(
        hb, wqb, nullptr, q, TOKENS, 256, DIM);
    // 2) routing (wave-parallel)
    topk_kernel<<<TOKENS, 256, 0, stream>>>(q, keys, eidx, wgt);
    // 3) g = hidden @ wgate^T -> bf16
    mfma_gemm<128, 128, 2, 2, 4, 4, 3><<<dim3(16, 16), 256, 0, stream>>>(
        hb, wgb, nullptr, g, TOKENS, INTER, DIM);
    // 4) act = silu(g) * (hidden @ wup^T) -> bf16
    mfma_gemm<128, 128, 2, 2, 4, 4, 1><<<dim3(16, 16), 256, 0, stream>>>(
        hb, wub, g, act, TOKENS, INTER, DIM);
    // 5) experts (writes estate over dead g)
    experts_kernel<<<TOKENS, 256, 0, stream>>>(hidden, down_e, up_e, eidx, wgt, estate);
    // 6) out = act @ wdown^T + estate  (2048 x 1024 x 2048)
    mfma_gemm<64, 128, 1, 4, 4, 2, 2><<<dim3(8, 32), 256, 0, stream>>>(
        act, wdb, estate, out, TOKENS, DIM, INTER);
}

// Round 7
// 242.700 us; speedup vs baseline: 2.7518x; 1.0162x over previous
//
#include <hip/hip_runtime.h>
#include <hip/hip_bf16.h>
#include <math.h>

// ---------------------------------------------------------------------------
// DogeCDMoE round 7: EXACT round-4 code (last pass, 246.6us) with ONE delta:
// gate/up GEMMs use 64x128 tile, grid(16,32) = 512 blocks = 2 blocks/CU
// (was 128x128, grid 256 = 1 block/CU -> no inter-block overlap, m114).
// Tile geometry <64,128,1,4,4,2> is already proven in this template (step 6).
// Also serves as bisect: isolates R5/R6 crash to {silu_mul|N=4096|aliasing}.
// ---------------------------------------------------------------------------

#define TOKENS 2048
#define DIM    1024
#define INTER  2048
#define NKEYS  128
#define TOPK   8
#define HEADS  4
#define NINF  -3.4e38f

typedef unsigned short ushort_t;
typedef __attribute__((ext_vector_type(8))) short bf16x8;
typedef __attribute__((ext_vector_type(4))) float f32x4;

__device__ __forceinline__ float bf2f(ushort_t u) {
    unsigned int x = (unsigned int)u << 16;
    float f; __builtin_memcpy(&f, &x, 4); return f;
}
__device__ __forceinline__ ushort_t f2bf_rne(float f) {
    unsigned int x; __builtin_memcpy(&x, &f, 4);
    x += 0x7fffu + ((x >> 16) & 1u);
    return (ushort_t)(x >> 16);
}
__device__ __forceinline__ void gload_lds16(const void* g, void* l) {
    __builtin_amdgcn_global_load_lds(
        (const __attribute__((address_space(1))) unsigned int*)g,
        (__attribute__((address_space(3))) unsigned int*)l, 16, 0, 0);
}

// ---------------- fused f32 -> bf16 (RNE) for all 5 tensors -----------------
__global__ __launch_bounds__(256) void convert_all(
    const float* __restrict__ h,  const float* __restrict__ wq,
    const float* __restrict__ wg, const float* __restrict__ wu,
    const float* __restrict__ wd,
    ushort_t* __restrict__ hb,  ushort_t* __restrict__ wqb,
    ushort_t* __restrict__ wgb, ushort_t* __restrict__ wub,
    ushort_t* __restrict__ wdb) {
    const int i = blockIdx.x * 256 + threadIdx.x;
    const float* src; ushort_t* dst; int off;
    if      (i <  262144) { src = h;  dst = hb;  off = i; }
    else if (i <  294912) { src = wq; dst = wqb; off = i - 262144; }
    else if (i <  557056) { src = wg; dst = wgb; off = i - 294912; }
    else if (i <  819200) { src = wu; dst = wub; off = i - 557056; }
    else                  { src = wd; dst = wdb; off = i - 819200; }
    const float4* p = (const float4*)src + (size_t)off * 2;
    const float4 a = p[0], b = p[1];
    uint4 o;
    o.x = (unsigned)f2bf_rne(a.x) | ((unsigned)f2bf_rne(a.y) << 16);
    o.y = (unsigned)f2bf_rne(a.z) | ((unsigned)f2bf_rne(a.w) << 16);
    o.z = (unsigned)f2bf_rne(b.x) | ((unsigned)f2bf_rne(b.y) << 16);
    o.w = (unsigned)f2bf_rne(b.z) | ((unsigned)f2bf_rne(b.w) << 16);
    ((uint4*)dst)[off] = o;
}

// ---------------- bf16 MFMA GEMM: C[M,N] = A[M,K] @ B[N,K]^T ----------------
// EPI 0: f32 = acc | 1: bf16 = silu(extra_bf16)*acc | 2: f32 = acc+extra_f32
// EPI 3: bf16 = acc
template<int BM, int BN, int WR, int WC, int FM, int FN, int EPI>
__global__ __launch_bounds__(256) void mfma_gemm(const ushort_t* __restrict__ A,
                                                 const ushort_t* __restrict__ B,
                                                 const void* __restrict__ extra,
                                                 void* __restrict__ Cout,
                                                 int M, int N, int K) {
    static_assert(WR * WC == 4 && WR * FM * 16 == BM && WC * FN * 16 == BN, "geom");
    __shared__ ushort_t As[BM * 32];
    __shared__ ushort_t Bs[BN * 32];
    const int tid = threadIdx.x;
    const int w = tid >> 6, lane = tid & 63;
    const int wr = w / WC, wc = w % WC;
    const int m0 = blockIdx.y * BM, n0 = blockIdx.x * BN;

    const int srow = (w << 4) + (lane >> 2);
    const int scol = (lane & 3) << 3;
    const ushort_t* Ag = &A[(size_t)(m0 + srow) * K + scol];
    const ushort_t* Bg = &B[(size_t)(n0 + srow) * K + scol];
    ushort_t* Al = &As[w << 9];
    ushort_t* Bl = &Bs[w << 9];

    const int frow = lane & 15;
    const int fcol = (lane >> 4) << 3;
    const ushort_t* Afr = &As[(size_t)(wr * FM * 16 + frow) * 32 + fcol];
    const ushort_t* Bfr = &Bs[(size_t)(wc * FN * 16 + frow) * 32 + fcol];

    f32x4 acc[FM][FN];
#pragma unroll
    for (int i = 0; i < FM; ++i)
#pragma unroll
        for (int j = 0; j < FN; ++j) acc[i][j] = (f32x4){0.f, 0.f, 0.f, 0.f};

    for (int k0 = 0; k0 < K; k0 += 32) {
        __syncthreads();
#pragma unroll
        for (int i = 0; i < BM / 64; ++i)
            gload_lds16(Ag + (size_t)i * 64 * K + k0, Al + i * 2048);
#pragma unroll
        for (int i = 0; i < BN / 64; ++i)
            gload_lds16(Bg + (size_t)i * 64 * K + k0, Bl + i * 2048);
        __syncthreads();

        bf16x8 af[FM], bfv[FN];
#pragma unroll
        for (int i = 0; i < FM; ++i) af[i] = *(const bf16x8*)(Afr + i * 512);
#pragma unroll
        for (int j = 0; j < FN; ++j) bfv[j] = *(const bf16x8*)(Bfr + j * 512);
#pragma unroll
        for (int i = 0; i < FM; ++i)
#pragma unroll
            for (int j = 0; j < FN; ++j)
                acc[i][j] = __builtin_amdgcn_mfma_f32_16x16x32_bf16(
                    af[i], bfv[j], acc[i][j], 0, 0, 0);
    }

    const int crow0 = m0 + wr * FM * 16 + ((lane >> 4) << 2);
    const int ccol0 = n0 + wc * FN * 16 + (lane & 15);
#pragma unroll
    for (int i = 0; i < FM; ++i)
#pragma unroll
        for (int j = 0; j < FN; ++j)
#pragma unroll
            for (int r = 0; r < 4; ++r) {
                const size_t off = (size_t)(crow0 + i * 16 + r) * N + ccol0 + j * 16;
                float v = acc[i][j][r];
                if (EPI == 1) {
                    const float gg = bf2f(((const ushort_t*)extra)[off]);
                    v *= gg / (1.f + __expf(-gg));
                    ((ushort_t*)Cout)[off] = f2bf_rne(v);
                } else if (EPI == 2) {
                    ((float*)Cout)[off] = v + ((const float*)extra)[off];
                } else if (EPI == 3) {
                    ((ushort_t*)Cout)[off] = f2bf_rne(v);
                } else {
                    ((float*)Cout)[off] = v;
                }
            }
}

// ---------------- wave-parallel product-key routing (unchanged) --------------
__global__ __launch_bounds__(256) void topk_kernel(const float* __restrict__ q,
                                                   const float* __restrict__ keys,
                                                   int* __restrict__ eidx,
                                                   float* __restrict__ ewgt) {
    const int t = blockIdx.x;
    const int head = threadIdx.x >> 6;
    const int lane = threadIdx.x & 63;

    const float4* qx = (const float4*)&q[(size_t)t * 256 + head * 32];
    const float4* qy = (const float4*)&q[(size_t)t * 256 + 128 + head * 32];
    float4 qxv[8], qyv[8];
#pragma unroll
    for (int n = 0; n < 8; ++n) { qxv[n] = qx[n]; qyv[n] = qy[n]; }

    float cx0, cx1, cy0, cy1;
    {
        float s[4];
#pragma unroll
        for (int j = 0; j < 2; ++j) {
            const int k = 2 * lane + j;
            const float4* kx = (const float4*)&keys[(size_t)(((head << 7) | k) * 2 + 0) * 32];
            const float4* ky = (const float4*)&keys[(size_t)(((head << 7) | k) * 2 + 1) * 32];
            float sx = 0.f, sy = 0.f;
#pragma unroll
            for (int n = 0; n < 8; ++n) {
                const float4 a = qxv[n], b = kx[n];
                sx += a.x * b.x + a.y * b.y + a.z * b.z + a.w * b.w;
                const float4 c = qyv[n], d = ky[n];
                sy += c.x * d.x + c.y * d.y + c.z * d.z + c.w * d.w;
            }
            s[j * 2] = sx; s[j * 2 + 1] = sy;
        }
        cx0 = s[0]; cy0 = s[1]; cx1 = s[2]; cy1 = s[3];
    }

    float sx_mine = NINF, sy_mine = NINF;
    int sxi_mine = 0, syi_mine = 0;
    {
        float c0 = cx0, c1 = cx1;
#pragma unroll
        for (int it = 0; it < TOPK; ++it) {
            float bv; int bi;
            if (c1 > c0) { bv = c1; bi = 2 * lane + 1; } else { bv = c0; bi = 2 * lane; }
#pragma unroll
            for (int m = 1; m < 64; m <<= 1) {
                const float ov = __shfl_xor(bv, m);
                const int   oi = __shfl_xor(bi, m);
                if (ov > bv || (ov == bv && oi < bi)) { bv = ov; bi = oi; }
            }
            if (lane == it) { sx_mine = bv; sxi_mine = bi; }
            if (bi == 2 * lane) c0 = NINF;
            else if (bi == 2 * lane + 1) c1 = NINF;
        }
    }
    {
        float c0 = cy0, c1 = cy1;
#pragma unroll
        for (int it = 0; it < TOPK; ++it) {
            float bv; int bi;
            if (c1 > c0) { bv = c1; bi = 2 * lane + 1; } else { bv = c0; bi = 2 * lane; }
#pragma unroll
            for (int m = 1; m < 64; m <<= 1) {
                const float ov = __shfl_xor(bv, m);
                const int   oi = __shfl_xor(bi, m);
                if (ov > bv || (ov == bv && oi < bi)) { bv = ov; bi = oi; }
            }
            if (lane == it) { sy_mine = bv; syi_mine = bi; }
            if (bi == 2 * lane) c0 = NINF;
            else if (bi == 2 * lane + 1) c1 = NINF;
        }
    }

    const float sa = __shfl(sx_mine, lane >> 3);
    const int   ia = __shfl(sxi_mine, lane >> 3);
    const float sb = __shfl(sy_mine, lane & 7);
    const int   ib = __shfl(syi_mine, lane & 7);
    float cv = sa + sb;
    const int ci = ia * NKEYS + ib;

    float fs_mine = NINF; int fi_mine = 0;
#pragma unroll
    for (int it = 0; it < TOPK; ++it) {
        float bv = cv; int bp = lane; int bx = ci;
#pragma unroll
        for (int m = 1; m < 64; m <<= 1) {
            const float ov = __shfl_xor(bv, m);
            const int   op = __shfl_xor(bp, m);
            const int   ox = __shfl_xor(bx, m);
            if (ov > bv || (ov == bv && op < bp)) { bv = ov; bp = op; bx = ox; }
        }
        if (lane == it) { fs_mine = bv; fi_mine = bx; }
        if (lane == bp) cv = NINF;
    }

    float f[8];
#pragma unroll
    for (int j = 0; j < 8; ++j) f[j] = __shfl(fs_mine, j);
    float mx = f[0];
#pragma unroll
    for (int j = 1; j < 8; ++j) mx = fmaxf(mx, f[j]);
    float ssum = 0.f;
#pragma unroll
    for (int j = 0; j < 8; ++j) ssum += expf(f[j] - mx);
    if (lane < 8) {
        eidx[t * 32 + head * 8 + lane] = fi_mine;
        ewgt[t * 32 + head * 8 + lane] = expf(fs_mine - mx) / ssum;
    }
}

// ---------------- experts: EXACT round-4 version (passed) -------------------
__global__ __launch_bounds__(256) void experts_kernel(const float* __restrict__ hs,
                                                      const float* __restrict__ down_embed,
                                                      const float* __restrict__ up_embed,
                                                      const int* __restrict__ eidx,
                                                      const float* __restrict__ ewgt,
                                                      float* __restrict__ estate) {
    __shared__ float4 partial[4][256];
    __shared__ int   eid[32];
    __shared__ float wl[32];
    const int t = blockIdx.x;
    const int tid = threadIdx.x;
    const int w = tid >> 6, lane = tid & 63;

    if (tid < 32) { eid[tid] = eidx[t * 32 + tid]; wl[tid] = ewgt[t * 32 + tid]; }

    const float4* hs4 = (const float4*)hs + (size_t)t * 256;
    float4 h[4];
#pragma unroll
    for (int i = 0; i < 4; ++i) h[i] = hs4[i * 64 + lane];

    const float4* de4 = (const float4*)down_embed;
    const float4* ue4 = (const float4*)up_embed;
    __syncthreads();

    float4 acc[4];
#pragma unroll
    for (int i = 0; i < 4; ++i) acc[i] = (float4){0.f, 0.f, 0.f, 0.f};

    float4 d[4], u[4], nd[4], nu[4];
    {
        const size_t b = (size_t)eid[w * 8] * 256;
#pragma unroll
        for (int i = 0; i < 4; ++i) { d[i] = de4[b + i * 64 + lane]; u[i] = ue4[b + i * 64 + lane]; }
    }
#pragma unroll
    for (int jj = 0; jj < 8; ++jj) {
        if (jj < 7) {
            const size_t b = (size_t)eid[w * 8 + jj + 1] * 256;
#pragma unroll
            for (int i = 0; i < 4; ++i) { nd[i] = de4[b + i * 64 + lane]; nu[i] = ue4[b + i * 64 + lane]; }
        }
        float s = 0.f;
#pragma unroll
        for (int i = 0; i < 4; ++i)
            s += h[i].x * d[i].x + h[i].y * d[i].y + h[i].z * d[i].z + h[i].w * d[i].w;
#pragma unroll
        for (int m = 1; m < 64; m <<= 1) s += __shfl_xor(s, m);
        const float c = (s / (1.f + __expf(-s))) * wl[w * 8 + jj];
#pragma unroll
        for (int i = 0; i < 4; ++i) {
            acc[i].x += c * u[i].x; acc[i].y += c * u[i].y;
            acc[i].z += c * u[i].z; acc[i].w += c * u[i].w;
        }
        if (jj < 7) {
#pragma unroll
            for (int i = 0; i < 4; ++i) { d[i] = nd[i]; u[i] = nu[i]; }
        }
    }

#pragma unroll
    for (int i = 0; i < 4; ++i) partial[w][i * 64 + lane] = acc[i];
    __syncthreads();

    const float4 p0 = partial[0][tid], p1 = partial[1][tid];
    const float4 p2 = partial[2][tid], p3 = partial[3][tid];
    float4 o;
    o.x = p0.x + p1.x + p2.x + p3.x;
    o.y = p0.y + p1.y + p2.y + p3.y;
    o.z = p0.z + p1.z + p2.z + p3.z;
    o.w = p0.w + p1.w + p2.w + p3.w;
    ((float4*)estate)[(size_t)t * 256 + tid] = o;
}

// ---------------------------------------------------------------------------
extern "C" void kernel_launch(void* const* d_in, const int* in_sizes, int n_in,
                              void* d_out, int out_size, void* d_ws, size_t ws_size,
                              hipStream_t stream) {
    (void)in_sizes; (void)n_in; (void)out_size; (void)ws_size;
    const float* hidden = (const float*)d_in[0];
    const float* wq     = (const float*)d_in[1];
    const float* keys   = (const float*)d_in[2];
    const float* down_e = (const float*)d_in[3];
    const float* up_e   = (const float*)d_in[4];
    const float* wgate  = (const float*)d_in[5];
    const float* wup    = (const float*)d_in[6];
    const float* wdown  = (const float*)d_in[7];
    float* out = (float*)d_out;
    char* ws = (char*)d_ws;

    // workspace layout: EXACT round-4 (passed). estate(f32,8MB) aliases
    // g(bf16,8MB): g dead after up-GEMM reads it; experts writes after.
    ushort_t* hb  = (ushort_t*)(ws);                     // 4 MB
    ushort_t* wqb = (ushort_t*)(ws + (4u << 20));        // 0.5 MB
    ushort_t* wgb = (ushort_t*)(ws + (4608u << 10));     // 4 MB
    ushort_t* wub = (ushort_t*)(ws + (8704u << 10));     // 4 MB
    ushort_t* wdb = (ushort_t*)(ws + (12800u << 10));    // 4 MB
    float*    q   = (float*)   (ws + (16896u << 10));    // 2 MB
    ushort_t* act = (ushort_t*)(ws + (18944u << 10));    // 8 MB
    ushort_t* g   = (ushort_t*)(ws + (27136u << 10));    // 8 MB
    float* estate = (float*)g;                           // alias
    float*    wgt = (float*)   (ws + (35328u << 10));    // 0.25 MB
    int*     eidx = (int*)     (ws + (35584u << 10));    // 0.25 MB

    convert_all<<<4224, 256, 0, stream>>>(hidden, wq, wgate, wup, wdown,
                                          hb, wqb, wgb, wub, wdb);

    // 1) q = hidden @ wq^T  (2048 x 256 x 1024), f32 out for routing
    mfma_gemm<64, 64, 2, 2, 2, 2, 0><<<dim3(4, 32), 256, 0, stream>>>(
        hb, wqb, nullptr, q, TOKENS, 256, DIM);
    // 2) routing (wave-parallel)
    topk_kernel<<<TOKENS, 256, 0, stream>>>(q, keys, eidx, wgt);
    // 3) g = hidden @ wgate^T -> bf16   [DELTA: 64x128 tile, 512 blocks]
    mfma_gemm<64, 128, 1, 4, 4, 2, 3><<<dim3(16, 32), 256, 0, stream>>>(
        hb, wgb, nullptr, g, TOKENS, INTER, DIM);
    // 4) act = silu(g) * (hidden @ wup^T) -> bf16   [DELTA: same]
    mfma_gemm<64, 128, 1, 4, 4, 2, 1><<<dim3(16, 32), 256, 0, stream>>>(
        hb, wub, g, act, TOKENS, INTER, DIM);
    // 5) experts (writes estate over dead g)
    experts_kernel<<<TOKENS, 256, 0, stream>>>(hidden, down_e, up_e, eidx, wgt, estate);
    // 6) out = act @ wdown^T + estate  (2048 x 1024 x 2048)
    mfma_gemm<64, 128, 1, 4, 4, 2, 2><<<dim3(8, 32), 256, 0, stream>>>(
        act, wdb, estate, out, TOKENS, DIM, INTER);
}

// Round 8
// 238.912 us; speedup vs baseline: 2.7954x; 1.0159x over previous
//
#include <hip/hip_runtime.h>
#include <hip/hip_bf16.h>
#include <math.h>

// ---------------------------------------------------------------------------
// DogeCDMoE round 8: EXACT round-7 file (passed, 242.7us) with ONE delta:
// experts_kernel __launch_bounds__(256) -> (256, 4). VGPR cap 64 -> 128 so the
// written 1-deep prefetch (~96 live VGPR) survives regalloc; 16 waves/CU.
// R6 crashing WITHOUT this change exonerates it from the R5 crash (lever A
// delta quarantined). Isolated test of the latency-bound experts theory.
// ---------------------------------------------------------------------------

#define TOKENS 2048
#define DIM    1024
#define INTER  2048
#define NKEYS  128
#define TOPK   8
#define HEADS  4
#define NINF  -3.4e38f

typedef unsigned short ushort_t;
typedef __attribute__((ext_vector_type(8))) short bf16x8;
typedef __attribute__((ext_vector_type(4))) float f32x4;

__device__ __forceinline__ float bf2f(ushort_t u) {
    unsigned int x = (unsigned int)u << 16;
    float f; __builtin_memcpy(&f, &x, 4); return f;
}
__device__ __forceinline__ ushort_t f2bf_rne(float f) {
    unsigned int x; __builtin_memcpy(&x, &f, 4);
    x += 0x7fffu + ((x >> 16) & 1u);
    return (ushort_t)(x >> 16);
}
__device__ __forceinline__ void gload_lds16(const void* g, void* l) {
    __builtin_amdgcn_global_load_lds(
        (const __attribute__((address_space(1))) unsigned int*)g,
        (__attribute__((address_space(3))) unsigned int*)l, 16, 0, 0);
}

// ---------------- fused f32 -> bf16 (RNE) for all 5 tensors -----------------
__global__ __launch_bounds__(256) void convert_all(
    const float* __restrict__ h,  const float* __restrict__ wq,
    const float* __restrict__ wg, const float* __restrict__ wu,
    const float* __restrict__ wd,
    ushort_t* __restrict__ hb,  ushort_t* __restrict__ wqb,
    ushort_t* __restrict__ wgb, ushort_t* __restrict__ wub,
    ushort_t* __restrict__ wdb) {
    const int i = blockIdx.x * 256 + threadIdx.x;
    const float* src; ushort_t* dst; int off;
    if      (i <  262144) { src = h;  dst = hb;  off = i; }
    else if (i <  294912) { src = wq; dst = wqb; off = i - 262144; }
    else if (i <  557056) { src = wg; dst = wgb; off = i - 294912; }
    else if (i <  819200) { src = wu; dst = wub; off = i - 557056; }
    else                  { src = wd; dst = wdb; off = i - 819200; }
    const float4* p = (const float4*)src + (size_t)off * 2;
    const float4 a = p[0], b = p[1];
    uint4 o;
    o.x = (unsigned)f2bf_rne(a.x) | ((unsigned)f2bf_rne(a.y) << 16);
    o.y = (unsigned)f2bf_rne(a.z) | ((unsigned)f2bf_rne(a.w) << 16);
    o.z = (unsigned)f2bf_rne(b.x) | ((unsigned)f2bf_rne(b.y) << 16);
    o.w = (unsigned)f2bf_rne(b.z) | ((unsigned)f2bf_rne(b.w) << 16);
    ((uint4*)dst)[off] = o;
}

// ---------------- bf16 MFMA GEMM: C[M,N] = A[M,K] @ B[N,K]^T ----------------
// EPI 0: f32 = acc | 1: bf16 = silu(extra_bf16)*acc | 2: f32 = acc+extra_f32
// EPI 3: bf16 = acc
template<int BM, int BN, int WR, int WC, int FM, int FN, int EPI>
__global__ __launch_bounds__(256) void mfma_gemm(const ushort_t* __restrict__ A,
                                                 const ushort_t* __restrict__ B,
                                                 const void* __restrict__ extra,
                                                 void* __restrict__ Cout,
                                                 int M, int N, int K) {
    static_assert(WR * WC == 4 && WR * FM * 16 == BM && WC * FN * 16 == BN, "geom");
    __shared__ ushort_t As[BM * 32];
    __shared__ ushort_t Bs[BN * 32];
    const int tid = threadIdx.x;
    const int w = tid >> 6, lane = tid & 63;
    const int wr = w / WC, wc = w % WC;
    const int m0 = blockIdx.y * BM, n0 = blockIdx.x * BN;

    const int srow = (w << 4) + (lane >> 2);
    const int scol = (lane & 3) << 3;
    const ushort_t* Ag = &A[(size_t)(m0 + srow) * K + scol];
    const ushort_t* Bg = &B[(size_t)(n0 + srow) * K + scol];
    ushort_t* Al = &As[w << 9];
    ushort_t* Bl = &Bs[w << 9];

    const int frow = lane & 15;
    const int fcol = (lane >> 4) << 3;
    const ushort_t* Afr = &As[(size_t)(wr * FM * 16 + frow) * 32 + fcol];
    const ushort_t* Bfr = &Bs[(size_t)(wc * FN * 16 + frow) * 32 + fcol];

    f32x4 acc[FM][FN];
#pragma unroll
    for (int i = 0; i < FM; ++i)
#pragma unroll
        for (int j = 0; j < FN; ++j) acc[i][j] = (f32x4){0.f, 0.f, 0.f, 0.f};

    for (int k0 = 0; k0 < K; k0 += 32) {
        __syncthreads();
#pragma unroll
        for (int i = 0; i < BM / 64; ++i)
            gload_lds16(Ag + (size_t)i * 64 * K + k0, Al + i * 2048);
#pragma unroll
        for (int i = 0; i < BN / 64; ++i)
            gload_lds16(Bg + (size_t)i * 64 * K + k0, Bl + i * 2048);
        __syncthreads();

        bf16x8 af[FM], bfv[FN];
#pragma unroll
        for (int i = 0; i < FM; ++i) af[i] = *(const bf16x8*)(Afr + i * 512);
#pragma unroll
        for (int j = 0; j < FN; ++j) bfv[j] = *(const bf16x8*)(Bfr + j * 512);
#pragma unroll
        for (int i = 0; i < FM; ++i)
#pragma unroll
            for (int j = 0; j < FN; ++j)
                acc[i][j] = __builtin_amdgcn_mfma_f32_16x16x32_bf16(
                    af[i], bfv[j], acc[i][j], 0, 0, 0);
    }

    const int crow0 = m0 + wr * FM * 16 + ((lane >> 4) << 2);
    const int ccol0 = n0 + wc * FN * 16 + (lane & 15);
#pragma unroll
    for (int i = 0; i < FM; ++i)
#pragma unroll
        for (int j = 0; j < FN; ++j)
#pragma unroll
            for (int r = 0; r < 4; ++r) {
                const size_t off = (size_t)(crow0 + i * 16 + r) * N + ccol0 + j * 16;
                float v = acc[i][j][r];
                if (EPI == 1) {
                    const float gg = bf2f(((const ushort_t*)extra)[off]);
                    v *= gg / (1.f + __expf(-gg));
                    ((ushort_t*)Cout)[off] = f2bf_rne(v);
                } else if (EPI == 2) {
                    ((float*)Cout)[off] = v + ((const float*)extra)[off];
                } else if (EPI == 3) {
                    ((ushort_t*)Cout)[off] = f2bf_rne(v);
                } else {
                    ((float*)Cout)[off] = v;
                }
            }
}

// ---------------- wave-parallel product-key routing (unchanged) --------------
__global__ __launch_bounds__(256) void topk_kernel(const float* __restrict__ q,
                                                   const float* __restrict__ keys,
                                                   int* __restrict__ eidx,
                                                   float* __restrict__ ewgt) {
    const int t = blockIdx.x;
    const int head = threadIdx.x >> 6;
    const int lane = threadIdx.x & 63;

    const float4* qx = (const float4*)&q[(size_t)t * 256 + head * 32];
    const float4* qy = (const float4*)&q[(size_t)t * 256 + 128 + head * 32];
    float4 qxv[8], qyv[8];
#pragma unroll
    for (int n = 0; n < 8; ++n) { qxv[n] = qx[n]; qyv[n] = qy[n]; }

    float cx0, cx1, cy0, cy1;
    {
        float s[4];
#pragma unroll
        for (int j = 0; j < 2; ++j) {
            const int k = 2 * lane + j;
            const float4* kx = (const float4*)&keys[(size_t)(((head << 7) | k) * 2 + 0) * 32];
            const float4* ky = (const float4*)&keys[(size_t)(((head << 7) | k) * 2 + 1) * 32];
            float sx = 0.f, sy = 0.f;
#pragma unroll
            for (int n = 0; n < 8; ++n) {
                const float4 a = qxv[n], b = kx[n];
                sx += a.x * b.x + a.y * b.y + a.z * b.z + a.w * b.w;
                const float4 c = qyv[n], d = ky[n];
                sy += c.x * d.x + c.y * d.y + c.z * d.z + c.w * d.w;
            }
            s[j * 2] = sx; s[j * 2 + 1] = sy;
        }
        cx0 = s[0]; cy0 = s[1]; cx1 = s[2]; cy1 = s[3];
    }

    float sx_mine = NINF, sy_mine = NINF;
    int sxi_mine = 0, syi_mine = 0;
    {
        float c0 = cx0, c1 = cx1;
#pragma unroll
        for (int it = 0; it < TOPK; ++it) {
            float bv; int bi;
            if (c1 > c0) { bv = c1; bi = 2 * lane + 1; } else { bv = c0; bi = 2 * lane; }
#pragma unroll
            for (int m = 1; m < 64; m <<= 1) {
                const float ov = __shfl_xor(bv, m);
                const int   oi = __shfl_xor(bi, m);
                if (ov > bv || (ov == bv && oi < bi)) { bv = ov; bi = oi; }
            }
            if (lane == it) { sx_mine = bv; sxi_mine = bi; }
            if (bi == 2 * lane) c0 = NINF;
            else if (bi == 2 * lane + 1) c1 = NINF;
        }
    }
    {
        float c0 = cy0, c1 = cy1;
#pragma unroll
        for (int it = 0; it < TOPK; ++it) {
            float bv; int bi;
            if (c1 > c0) { bv = c1; bi = 2 * lane + 1; } else { bv = c0; bi = 2 * lane; }
#pragma unroll
            for (int m = 1; m < 64; m <<= 1) {
                const float ov = __shfl_xor(bv, m);
                const int   oi = __shfl_xor(bi, m);
                if (ov > bv || (ov == bv && oi < bi)) { bv = ov; bi = oi; }
            }
            if (lane == it) { sy_mine = bv; syi_mine = bi; }
            if (bi == 2 * lane) c0 = NINF;
            else if (bi == 2 * lane + 1) c1 = NINF;
        }
    }

    const float sa = __shfl(sx_mine, lane >> 3);
    const int   ia = __shfl(sxi_mine, lane >> 3);
    const float sb = __shfl(sy_mine, lane & 7);
    const int   ib = __shfl(syi_mine, lane & 7);
    float cv = sa + sb;
    const int ci = ia * NKEYS + ib;

    float fs_mine = NINF; int fi_mine = 0;
#pragma unroll
    for (int it = 0; it < TOPK; ++it) {
        float bv = cv; int bp = lane; int bx = ci;
#pragma unroll
        for (int m = 1; m < 64; m <<= 1) {
            const float ov = __shfl_xor(bv, m);
            const int   op = __shfl_xor(bp, m);
            const int   ox = __shfl_xor(bx, m);
            if (ov > bv || (ov == bv && op < bp)) { bv = ov; bp = op; bx = ox; }
        }
        if (lane == it) { fs_mine = bv; fi_mine = bx; }
        if (lane == bp) cv = NINF;
    }

    float f[8];
#pragma unroll
    for (int j = 0; j < 8; ++j) f[j] = __shfl(fs_mine, j);
    float mx = f[0];
#pragma unroll
    for (int j = 1; j < 8; ++j) mx = fmaxf(mx, f[j]);
    float ssum = 0.f;
#pragma unroll
    for (int j = 0; j < 8; ++j) ssum += expf(f[j] - mx);
    if (lane < 8) {
        eidx[t * 32 + head * 8 + lane] = fi_mine;
        ewgt[t * 32 + head * 8 + lane] = expf(fs_mine - mx) / ssum;
    }
}

// ---------------- experts: R4 body + launch_bounds(256,4) [THE DELTA] -------
__global__ __launch_bounds__(256, 4) void experts_kernel(const float* __restrict__ hs,
                                                      const float* __restrict__ down_embed,
                                                      const float* __restrict__ up_embed,
                                                      const int* __restrict__ eidx,
                                                      const float* __restrict__ ewgt,
                                                      float* __restrict__ estate) {
    __shared__ float4 partial[4][256];
    __shared__ int   eid[32];
    __shared__ float wl[32];
    const int t = blockIdx.x;
    const int tid = threadIdx.x;
    const int w = tid >> 6, lane = tid & 63;

    if (tid < 32) { eid[tid] = eidx[t * 32 + tid]; wl[tid] = ewgt[t * 32 + tid]; }

    const float4* hs4 = (const float4*)hs + (size_t)t * 256;
    float4 h[4];
#pragma unroll
    for (int i = 0; i < 4; ++i) h[i] = hs4[i * 64 + lane];

    const float4* de4 = (const float4*)down_embed;
    const float4* ue4 = (const float4*)up_embed;
    __syncthreads();

    float4 acc[4];
#pragma unroll
    for (int i = 0; i < 4; ++i) acc[i] = (float4){0.f, 0.f, 0.f, 0.f};

    float4 d[4], u[4], nd[4], nu[4];
    {
        const size_t b = (size_t)eid[w * 8] * 256;
#pragma unroll
        for (int i = 0; i < 4; ++i) { d[i] = de4[b + i * 64 + lane]; u[i] = ue4[b + i * 64 + lane]; }
    }
#pragma unroll
    for (int jj = 0; jj < 8; ++jj) {
        if (jj < 7) {
            const size_t b = (size_t)eid[w * 8 + jj + 1] * 256;
#pragma unroll
            for (int i = 0; i < 4; ++i) { nd[i] = de4[b + i * 64 + lane]; nu[i] = ue4[b + i * 64 + lane]; }
        }
        float s = 0.f;
#pragma unroll
        for (int i = 0; i < 4; ++i)
            s += h[i].x * d[i].x + h[i].y * d[i].y + h[i].z * d[i].z + h[i].w * d[i].w;
#pragma unroll
        for (int m = 1; m < 64; m <<= 1) s += __shfl_xor(s, m);
        const float c = (s / (1.f + __expf(-s))) * wl[w * 8 + jj];
#pragma unroll
        for (int i = 0; i < 4; ++i) {
            acc[i].x += c * u[i].x; acc[i].y += c * u[i].y;
            acc[i].z += c * u[i].z; acc[i].w += c * u[i].w;
        }
        if (jj < 7) {
#pragma unroll
            for (int i = 0; i < 4; ++i) { d[i] = nd[i]; u[i] = nu[i]; }
        }
    }

#pragma unroll
    for (int i = 0; i < 4; ++i) partial[w][i * 64 + lane] = acc[i];
    __syncthreads();

    const float4 p0 = partial[0][tid], p1 = partial[1][tid];
    const float4 p2 = partial[2][tid], p3 = partial[3][tid];
    float4 o;
    o.x = p0.x + p1.x + p2.x + p3.x;
    o.y = p0.y + p1.y + p2.y + p3.y;
    o.z = p0.z + p1.z + p2.z + p3.z;
    o.w = p0.w + p1.w + p2.w + p3.w;
    ((float4*)estate)[(size_t)t * 256 + tid] = o;
}

// ---------------------------------------------------------------------------
extern "C" void kernel_launch(void* const* d_in, const int* in_sizes, int n_in,
                              void* d_out, int out_size, void* d_ws, size_t ws_size,
                              hipStream_t stream) {
    (void)in_sizes; (void)n_in; (void)out_size; (void)ws_size;
    const float* hidden = (const float*)d_in[0];
    const float* wq     = (const float*)d_in[1];
    const float* keys   = (const float*)d_in[2];
    const float* down_e = (const float*)d_in[3];
    const float* up_e   = (const float*)d_in[4];
    const float* wgate  = (const float*)d_in[5];
    const float* wup    = (const float*)d_in[6];
    const float* wdown  = (const float*)d_in[7];
    float* out = (float*)d_out;
    char* ws = (char*)d_ws;

    // workspace layout: EXACT round-4/7 (passed). estate(f32,8MB) aliases
    // g(bf16,8MB): g dead after up-GEMM reads it; experts writes after.
    ushort_t* hb  = (ushort_t*)(ws);                     // 4 MB
    ushort_t* wqb = (ushort_t*)(ws + (4u << 20));        // 0.5 MB
    ushort_t* wgb = (ushort_t*)(ws + (4608u << 10));     // 4 MB
    ushort_t* wub = (ushort_t*)(ws + (8704u << 10));     // 4 MB
    ushort_t* wdb = (ushort_t*)(ws + (12800u << 10));    // 4 MB
    float*    q   = (float*)   (ws + (16896u << 10));    // 2 MB
    ushort_t* act = (ushort_t*)(ws + (18944u << 10));    // 8 MB
    ushort_t* g   = (ushort_t*)(ws + (27136u << 10));    // 8 MB
    float* estate = (float*)g;                           // alias
    float*    wgt = (float*)   (ws + (35328u << 10));    // 0.25 MB
    int*     eidx = (int*)     (ws + (35584u << 10));    // 0.25 MB

    convert_all<<<4224, 256, 0, stream>>>(hidden, wq, wgate, wup, wdown,
                                          hb, wqb, wgb, wub, wdb);

    // 1) q = hidden @ wq^T  (2048 x 256 x 1024), f32 out for routing
    mfma_gemm<64, 64, 2, 2, 2, 2, 0><<<dim3(4, 32), 256, 0, stream>>>(
        hb, wqb, nullptr, q, TOKENS, 256, DIM);
    // 2) routing (wave-parallel)
    topk_kernel<<<TOKENS, 256, 0, stream>>>(q, keys, eidx, wgt);
    // 3) g = hidden @ wgate^T -> bf16
    mfma_gemm<64, 128, 1, 4, 4, 2, 3><<<dim3(16, 32), 256, 0, stream>>>(
        hb, wgb, nullptr, g, TOKENS, INTER, DIM);
    // 4) act = silu(g) * (hidden @ wup^T) -> bf16
    mfma_gemm<64, 128, 1, 4, 4, 2, 1><<<dim3(16, 32), 256, 0, stream>>>(
        hb, wub, g, act, TOKENS, INTER, DIM);
    // 5) experts (writes estate over dead g)
    experts_kernel<<<TOKENS, 256, 0, stream>>>(hidden, down_e, up_e, eidx, wgt, estate);
    // 6) out = act @ wdown^T + estate  (2048 x 1024 x 2048)
    mfma_gemm<64, 128, 1, 4, 4, 2, 2><<<dim3(8, 32), 256, 0, stream>>>(
        act, wdb, estate, out, TOKENS, DIM, INTER);
}